// Round 10
// baseline (578.828 us; speedup 1.0000x reference)
//
#include <hip/hip_runtime.h>
#include <math.h>

typedef __bf16 bf16;
typedef __attribute__((ext_vector_type(8))) __bf16 bf16x8;
typedef __attribute__((ext_vector_type(4))) __bf16 bf16x4;
typedef __attribute__((ext_vector_type(4))) float f32x4;

#define NCH1 128  // row chunks for bn1 stats
#define RPC1 16   // rows per chunk

// rel-PE table domain: covers ln(1e-3) .. ln(57.5) and dw/dh range
#define XD0   (-6.93f)
#define XSPAN (11.03f)
#define XINVH (1023.f / 11.03f)

// ---------------------------------------------------------------------------
// prep mega-kernel: 901 blocks (also zeroes the grid-barrier counters)
// ---------------------------------------------------------------------------
__global__ __launch_bounds__(256)
void prep(const float* __restrict__ Wq, const float* __restrict__ Wk, const float* __restrict__ Wv,
          bf16* __restrict__ T0, bf16* __restrict__ T1, bf16* __restrict__ T2,
          const float* __restrict__ bq, const float* __restrict__ bk, float* __restrict__ biasqk,
          const float* __restrict__ X, float* __restrict__ psum, float* __restrict__ psq,
          const float* __restrict__ boxes, const float* __restrict__ Wr, const float* __restrict__ br,
          float* __restrict__ ent, float* __restrict__ tabs, unsigned* __restrict__ barctr)
{
    __shared__ float tile[64][65];
    const int bid = blockIdx.x;
    const int tid = threadIdx.x;

    if (bid < 768) {                       // ---- weight transpose+cvt
        const int mat = bid >> 8, g2 = bid & 255;
        const float* W = (mat == 0) ? Wq : (mat == 1) ? Wk : Wv;
        bf16* T        = (mat == 0) ? T0 : (mat == 1) ? T1 : T2;
        const int bx = (g2 & 15) * 64, by = (g2 >> 4) * 64;
        const int tx = tid & 63, ty = tid >> 6;
#pragma unroll
        for (int i = 0; i < 16; ++i)
            tile[ty + i * 4][tx] = W[(long)(by + ty + i * 4) * 1024 + bx + tx];
        __syncthreads();
#pragma unroll
        for (int i = 0; i < 16; ++i)
            T[(long)(bx + ty + i * 4) * 1024 + by + tx] = (bf16)tile[tx][ty + i * 4];
    } else if (bid < 896) {                // ---- bn1 colstats partial
        const int c4 = tid;
        const long r0 = (long)(bid - 768) * RPC1;
        const float4* Xv = (const float4*)X;
        float4 s = {0.f,0.f,0.f,0.f}, q = {0.f,0.f,0.f,0.f};
#pragma unroll
        for (int r = 0; r < RPC1; ++r) {
            float4 x = Xv[(r0 + r) * 256 + c4];
            s.x += x.x; s.y += x.y; s.z += x.z; s.w += x.w;
            q.x += x.x*x.x; q.y += x.y*x.y; q.z += x.z*x.z; q.w += x.w*x.w;
        }
        ((float4*)psum)[(bid - 768) * 256 + c4] = s;
        ((float4*)psq) [(bid - 768) * 256 + c4] = q;
    } else if (bid == 896) {               // ---- entity values + bias pack + barrier reset
        for (int e = tid; e < 2048; e += 256) {
            float4 b4 = ((const float4*)boxes)[e];
            float w = b4.z, h = b4.w;
            ent[0*2048+e] = b4.x + 0.5f * w;   // cx
            ent[1*2048+e] = b4.y + 0.5f * h;   // cy
            ent[2*2048+e] = __logf(w);         // lw
            ent[3*2048+e] = __logf(h);         // lh
            ent[4*2048+e] = 1e-3f * w;         // ew
            ent[5*2048+e] = 1e-3f * h;         // eh
        }
        for (int i = tid; i < 2048; i += 256)
            biasqk[i] = (i < 1024) ? bq[i] : bk[i - 1024];
        if (tid < 8) barctr[tid] = 0u;
        if (tid < 8) __threadfence();
    } else {                               // ---- rel tables per weight slot
        const int c = bid - 897;           // weight slot 0..3
        float* tb = tabs + c * 1024;
        const float brq = 0.25f * br[0];
        const float hstep = XSPAN / 1023.f;
        for (int e = tid; e < 1024; e += 256) {
            float d = XD0 + hstep * (float)e;
            float a = brq;
#pragma unroll
            for (int k = 0; k < 16; ++k) {
                float tk = exp2f(-1.24572303558f * (float)k);  // 1000^(-k/8)
                float s_, c_;
                __sincosf(d * tk, &s_, &c_);
                a += s_ * Wr[c * 32 + k] + c_ * Wr[c * 32 + 16 + k];
            }
            tb[e] = a;
        }
    }
}

// ------- fused: finalize bn1 stats (per 64-col stripe) + apply --------------
__global__ __launch_bounds__(256)
void bn1_final_apply(const float* __restrict__ X, const float* __restrict__ psum,
                     const float* __restrict__ psq, const float* __restrict__ g,
                     const float* __restrict__ b, bf16* __restrict__ Yp)
{
    __shared__ float ls[4][64], lq[4][64], ssc[64], ssh[64];
    const int t  = threadIdx.x;
    const int cs = blockIdx.x;
    const int rc = blockIdx.y;
    const int col_l = t & 63, part = t >> 6;
    const int col = cs * 64 + col_l;
    float s = 0.f, q = 0.f;
#pragma unroll
    for (int i = 0; i < 32; ++i) {
        int ch = part * 32 + i;
        s += psum[ch * 1024 + col];
        q += psq [ch * 1024 + col];
    }
    ls[part][col_l] = s; lq[part][col_l] = q;
    __syncthreads();
    if (t < 64) {
        float S = ls[0][t]+ls[1][t]+ls[2][t]+ls[3][t];
        float Q = lq[0][t]+lq[1][t]+lq[2][t]+lq[3][t];
        float m = S / 2048.f;
        float v = Q / 2048.f - m*m;
        float inv = 1.0f / sqrtf(v + 1e-5f);
        float sc = g[cs*64+t] * inv;
        ssc[t] = sc; ssh[t] = b[cs*64+t] - m*sc;
    }
    __syncthreads();
    const int f = t & 15, rsub = t >> 4;
    float4 sc4 = ((const float4*)ssc)[f];
    float4 sh4 = ((const float4*)ssh)[f];
#pragma unroll
    for (int it = 0; it < 8; ++it) {
        int row = rc*128 + it*16 + rsub;
        float4 x = ((const float4*)(X + (long)row*1024 + cs*64))[f];
        bf16x4 y;
        y[0]=(bf16)(x.x*sc4.x + sh4.x);
        y[1]=(bf16)(x.y*sc4.y + sh4.y);
        y[2]=(bf16)(x.z*sc4.z + sh4.z);
        y[3]=(bf16)(x.w*sc4.w + sh4.w);
        ((bf16x4*)(Yp + (long)row*1024 + cs*64))[f] = y;
    }
}

// ---------------- rel table lookup ------------------------------------------
__device__ __forceinline__ float look(const float* tab, float d)
{
    float t = (d - XD0) * XINVH;
    t = fminf(fmaxf(t, 0.f), 1022.999f);
    float fi = floorf(t);
    int i = (int)fi;
    float a = tab[i], b = tab[i + 1];
    return a + (b - a) * (t - fi);
}

// ---------------- staging helpers -------------------------------------------
__device__ __forceinline__ void stage_tile_128x32(const bf16* __restrict__ src_base, int ld,
                                                  int row0, int k0, bf16* lds_base, int w, int l)
{
#pragma unroll
    for (int t = 0; t < 2; ++t) {
        int rchunk = w * 32 + t * 16;
        const bf16* src = src_base + (long)(row0 + rchunk + (l >> 2)) * ld + k0 + (l & 3) * 8;
        __builtin_amdgcn_global_load_lds((__attribute__((address_space(1))) void*)src,
                                         (__attribute__((address_space(3))) void*)(lds_base + rchunk * 32),
                                         16, 0, 0);
    }
}

__device__ __forceinline__ void stage64(const bf16* __restrict__ src_base, int ld,
                                        int row0, int k0, bf16* lds_base, int w, int l)
{
    const bf16* src = src_base + (long)(row0 + w * 16 + (l >> 2)) * ld + k0 + (l & 3) * 8;
    __builtin_amdgcn_global_load_lds((__attribute__((address_space(1))) void*)src,
                                     (__attribute__((address_space(3))) void*)(lds_base + w * 16 * 32),
                                     16, 0, 0);
}

// ---------------- 128x64 MFMA GEMM body: C = A(M,K) @ BT(N,K)^T -------------
// MODE 0: bf16 out +bias[col]    1: bf16 out +bias[row]
template <int MODE>
__device__ __forceinline__ void gemm_12864(
    const bf16* __restrict__ Ab, int lda, const bf16* __restrict__ Bb, int ldb,
    bf16* __restrict__ Cp, int ldc, int K, int bm, int bn,
    const float* __restrict__ bias, char* smem)
{
    bf16* As0 = (bf16*)smem;             // [2][128*32] 16KB
    bf16* Bs0 = (bf16*)(smem + 16384);   // [2][64*32]   8KB
    const int tid = threadIdx.x;
    const int w = tid >> 6, l = tid & 63;
    const int wr = w >> 1, wc = w & 1;

    f32x4 acc[4][2];
#pragma unroll
    for (int i = 0; i < 4; ++i)
#pragma unroll
        for (int j = 0; j < 2; ++j) acc[i][j] = (f32x4){0.f,0.f,0.f,0.f};

    const int nkt = K >> 5;
    stage_tile_128x32(Ab, lda, bm, 0, As0, w, l);
    stage64(Bb, ldb, bn, 0, Bs0, w, l);
    __syncthreads();

    const int fr = l & 15;
    const int ko = (l >> 4) * 8;

    for (int kt = 0; kt < nkt; ++kt) {
        const int cur = kt & 1;
        bf16* Asc = As0 + cur * 4096;
        bf16* Bsc = Bs0 + cur * 2048;
        if (kt + 1 < nkt) {
            stage_tile_128x32(Ab, lda, bm, (kt + 1) << 5, As0 + (cur ^ 1) * 4096, w, l);
            stage64(Bb, ldb, bn, (kt + 1) << 5, Bs0 + (cur ^ 1) * 2048, w, l);
        }
        bf16x8 af[4], bfv[2];
#pragma unroll
        for (int mi = 0; mi < 4; ++mi)
            af[mi] = *(const bf16x8*)(&Asc[(wr * 64 + mi * 16 + fr) * 32 + ko]);
#pragma unroll
        for (int ni = 0; ni < 2; ++ni)
            bfv[ni] = *(const bf16x8*)(&Bsc[(wc * 32 + ni * 16 + fr) * 32 + ko]);
#pragma unroll
        for (int mi = 0; mi < 4; ++mi)
#pragma unroll
            for (int ni = 0; ni < 2; ++ni)
                acc[mi][ni] = __builtin_amdgcn_mfma_f32_16x16x32_bf16(af[mi], bfv[ni], acc[mi][ni], 0, 0, 0);
        __syncthreads();
    }

    const int crow0 = bm + wr * 64 + (l >> 4) * 4;
    const int ccol0 = bn + wc * 32 + fr;
#pragma unroll
    for (int mi = 0; mi < 4; ++mi)
#pragma unroll
        for (int ni = 0; ni < 2; ++ni)
#pragma unroll
            for (int r = 0; r < 4; ++r) {
                const int row = crow0 + mi * 16 + r;
                const int col = ccol0 + ni * 16;
                const float v = acc[mi][ni][r];
                if constexpr (MODE == 0) {
                    Cp[(long)row * ldc + col] = (bf16)(v + bias[col]);
                } else {
                    Cp[(long)row * ldc + col] = (bf16)(v + bias[row]);
                }
            }
}

// ---------------- attn body: S tile = q@k^T/32 (+rel on kh==0) --------------
__device__ __forceinline__ void attn_body(
    const bf16* __restrict__ qk, float* __restrict__ S0, float* __restrict__ S1,
    const float* __restrict__ ent, const float* __restrict__ tabs,
    int bx, int by, int bz, char* smem)
{
    const int img = bz >> 1, kh = bz & 1;
    const int bm = bx * 64, bn = by * 64;
    const bf16* A = qk + (long)img * 1048576 + kh * 512;
    const bf16* B = qk + 1024 + (long)img * 1048576 + kh * 512;
    bf16* As0 = (bf16*)smem;            // [2][64*32]
    bf16* Bs0 = (bf16*)(smem + 8192);

    const int tid = threadIdx.x;
    const int w = tid >> 6, l = tid & 63;
    const int wr = w >> 1, wc = w & 1;
    const int fr = l & 15;
    const int ko = (l >> 4) * 8;

    f32x4 acc[2][2];
#pragma unroll
    for (int i = 0; i < 2; ++i)
#pragma unroll
        for (int j = 0; j < 2; ++j) acc[i][j] = (f32x4){0.f,0.f,0.f,0.f};

    stage64(A, 2048, bm, 0, As0, w, l);
    stage64(B, 2048, bn, 0, Bs0, w, l);
    __syncthreads();

    for (int kt = 0; kt < 16; ++kt) {
        const int cur = kt & 1;
        bf16* Asc = As0 + cur * 2048;
        bf16* Bsc = Bs0 + cur * 2048;
        if (kt + 1 < 16) {
            stage64(A, 2048, bm, (kt + 1) << 5, As0 + (cur ^ 1) * 2048, w, l);
            stage64(B, 2048, bn, (kt + 1) << 5, Bs0 + (cur ^ 1) * 2048, w, l);
        }
        bf16x8 af[2], bfv[2];
#pragma unroll
        for (int mi = 0; mi < 2; ++mi)
            af[mi] = *(const bf16x8*)(&Asc[(wr * 32 + mi * 16 + fr) * 32 + ko]);
#pragma unroll
        for (int ni = 0; ni < 2; ++ni)
            bfv[ni] = *(const bf16x8*)(&Bsc[(wc * 32 + ni * 16 + fr) * 32 + ko]);
#pragma unroll
        for (int mi = 0; mi < 2; ++mi)
#pragma unroll
            for (int ni = 0; ni < 2; ++ni)
                acc[mi][ni] = __builtin_amdgcn_mfma_f32_16x16x32_bf16(af[mi], bfv[ni], acc[mi][ni], 0, 0, 0);
        __syncthreads();
    }

    const float scale = 0.03125f;
    float* Sout = (kh == 0 ? S0 : S1) + (long)img * 262144;

    if (kh == 1) {
#pragma unroll
        for (int mi = 0; mi < 2; ++mi)
#pragma unroll
            for (int ni = 0; ni < 2; ++ni)
#pragma unroll
                for (int r = 0; r < 4; ++r) {
                    const int rowl = wr * 32 + mi * 16 + (l >> 4) * 4 + r;
                    const int coll = wc * 32 + ni * 16 + fr;
                    Sout[(long)(bm + rowl) * 512 + bn + coll] = acc[mi][ni][r] * scale;
                }
        return;
    }

    // kh==0: add rel bias (reshape-quirk semantics). b = col>>7 uniform per tile.
    float* stab = (float*)smem;        // 4096 floats (16KB)
    float* RA   = stab + 4096;         // 64 row-entity values
    float* SA   = RA + 64;             // 260 source-entity values
    float* SE   = SA + 260;
    float* SL   = SE + 260;
    const int b   = bn >> 7;
    const int jj0 = (bn & 64) * 4;     // 0 or 256
    for (int i = tid; i < 4096; i += 256) stab[i] = tabs[i];
    {
        const int eb = img * 512;
        if (tid < 64) RA[tid] = ent[b * 2048 + eb + bm + tid];
        for (int u = tid; u < 260 && jj0 + u < 512; u += 256) {
            SA[u] = ent[b * 2048 + eb + jj0 + u];
            if (b < 2) {
                SE[u] = ent[(4 + b) * 2048 + eb + jj0 + u];
                SL[u] = ent[(2 + b) * 2048 + eb + jj0 + u];
            }
        }
    }
    __syncthreads();
#pragma unroll
    for (int ni = 0; ni < 2; ++ni) {
        const int coll = wc * 32 + ni * 16 + fr;
        const int u0   = 4 * coll;
        const float sA0 = SA[u0], sA1 = SA[u0+1], sA2 = SA[u0+2], sA3 = SA[u0+3];
        float sE0=0.f,sE1=0.f,sE2=0.f,sE3=0.f, sL0=0.f,sL1=0.f,sL2=0.f,sL3=0.f;
        if (b < 2) {
            sE0 = SE[u0]; sE1 = SE[u0+1]; sE2 = SE[u0+2]; sE3 = SE[u0+3];
            sL0 = SL[u0]; sL1 = SL[u0+1]; sL2 = SL[u0+2]; sL3 = SL[u0+3];
        }
#pragma unroll
        for (int mi = 0; mi < 2; ++mi)
#pragma unroll
            for (int r = 0; r < 4; ++r) {
                const int rowl = wr * 32 + mi * 16 + (l >> 4) * 4 + r;
                const float ai = RA[rowl];
                float d0, d1, d2, d3;
                if (b < 2) {
                    d0 = __logf(fmaxf(fabsf(ai - sA0), sE0)) - sL0;
                    d1 = __logf(fmaxf(fabsf(ai - sA1), sE1)) - sL1;
                    d2 = __logf(fmaxf(fabsf(ai - sA2), sE2)) - sL2;
                    d3 = __logf(fmaxf(fabsf(ai - sA3), sE3)) - sL3;
                } else {
                    d0 = ai - sA0; d1 = ai - sA1; d2 = ai - sA2; d3 = ai - sA3;
                }
                float relv = look(stab,        d0) + look(stab + 1024, d1)
                           + look(stab + 2048, d2) + look(stab + 3072, d3);
                Sout[(long)(bm + rowl) * 512 + bn + coll] = acc[mi][ni][r] * scale + relv;
            }
    }
}

// ---------------- pv body: out tile = P@vT^T + bn2 column partials ----------
__device__ __forceinline__ void pv_body(
    const bf16* __restrict__ P, const bf16* __restrict__ vT, float* __restrict__ out,
    float* __restrict__ psum, float* __restrict__ psq,
    int mt, int nt, int img, char* smem)
{
    const int bm = mt * 64, bn = nt * 64;
    const bf16* A = P  + (long)img * 262144;   // 512x512
    const bf16* B = vT + (long)img * 524288;   // 1024x512
    float* C = out + (long)img * 524288;
    bf16* As0 = (bf16*)smem;
    bf16* Bs0 = (bf16*)(smem + 8192);

    const int tid = threadIdx.x;
    const int w = tid >> 6, l = tid & 63;
    const int wr = w >> 1, wc = w & 1;
    const int fr = l & 15;
    const int ko = (l >> 4) * 8;

    f32x4 acc[2][2];
#pragma unroll
    for (int i = 0; i < 2; ++i)
#pragma unroll
        for (int j = 0; j < 2; ++j) acc[i][j] = (f32x4){0.f,0.f,0.f,0.f};

    stage64(A, 512, bm, 0, As0, w, l);
    stage64(B, 512, bn, 0, Bs0, w, l);
    __syncthreads();

    for (int kt = 0; kt < 16; ++kt) {
        const int cur = kt & 1;
        bf16* Asc = As0 + cur * 2048;
        bf16* Bsc = Bs0 + cur * 2048;
        if (kt + 1 < 16) {
            stage64(A, 512, bm, (kt + 1) << 5, As0 + (cur ^ 1) * 2048, w, l);
            stage64(B, 512, bn, (kt + 1) << 5, Bs0 + (cur ^ 1) * 2048, w, l);
        }
        bf16x8 af[2], bfv[2];
#pragma unroll
        for (int mi = 0; mi < 2; ++mi)
            af[mi] = *(const bf16x8*)(&Asc[(wr * 32 + mi * 16 + fr) * 32 + ko]);
#pragma unroll
        for (int ni = 0; ni < 2; ++ni)
            bfv[ni] = *(const bf16x8*)(&Bsc[(wc * 32 + ni * 16 + fr) * 32 + ko]);
#pragma unroll
        for (int mi = 0; mi < 2; ++mi)
#pragma unroll
            for (int ni = 0; ni < 2; ++ni)
                acc[mi][ni] = __builtin_amdgcn_mfma_f32_16x16x32_bf16(af[mi], bfv[ni], acc[mi][ni], 0, 0, 0);
        __syncthreads();
    }

#pragma unroll
    for (int mi = 0; mi < 2; ++mi)
#pragma unroll
        for (int ni = 0; ni < 2; ++ni)
#pragma unroll
            for (int r = 0; r < 4; ++r) {
                const int rowl = wr * 32 + mi * 16 + (l >> 4) * 4 + r;
                const int coll = wc * 32 + ni * 16 + fr;
                C[(long)(bm + rowl) * 1024 + bn + coll] = acc[mi][ni][r];
            }

    float s_[2], q_[2];
#pragma unroll
    for (int ni = 0; ni < 2; ++ni) {
        float s = 0.f, q = 0.f;
#pragma unroll
        for (int mi = 0; mi < 2; ++mi)
#pragma unroll
            for (int r = 0; r < 4; ++r) { float v = acc[mi][ni][r]; s += v; q += v * v; }
        s_[ni] = s; q_[ni] = q;
    }
#pragma unroll
    for (int ni = 0; ni < 2; ++ni) {
        s_[ni] += __shfl_xor(s_[ni], 16); s_[ni] += __shfl_xor(s_[ni], 32);
        q_[ni] += __shfl_xor(q_[ni], 16); q_[ni] += __shfl_xor(q_[ni], 32);
    }
    float* lred = (float*)smem;
    __syncthreads();
    if (l < 16) {
#pragma unroll
        for (int ni = 0; ni < 2; ++ni) {
            const int c = wc * 32 + ni * 16 + l;
            lred[(wr * 2 + 0) * 64 + c] = s_[ni];
            lred[(wr * 2 + 1) * 64 + c] = q_[ni];
        }
    }
    __syncthreads();
    if (tid < 64) {
        const int chunk = img * 8 + mt;
        psum[chunk * 1024 + bn + tid] = lred[0 * 64 + tid] + lred[2 * 64 + tid];
        psq [chunk * 1024 + bn + tid] = lred[1 * 64 + tid] + lred[3 * 64 + tid];
    }
}

// ---------------- grid barrier (device-scope, persistent kernel) ------------
__device__ __forceinline__ void gridbar(unsigned* __restrict__ ctr, unsigned target)
{
    __threadfence();
    __syncthreads();
    if (threadIdx.x == 0) {
        atomicAdd(ctr, 1u);
        while (__hip_atomic_load(ctr, __ATOMIC_ACQUIRE, __HIP_MEMORY_SCOPE_AGENT) < target)
            __builtin_amdgcn_s_sleep(2);
    }
    __syncthreads();
    __threadfence();
}

// ---------------- persistent mega-kernel: qk+vT -> attn -> softmax -> pv -> bn2
// 512 blocks, 2/CU guaranteed co-resident.
__global__ __launch_bounds__(256, 2)
void mega(const bf16* __restrict__ featbf, const bf16* __restrict__ WqkT,
          const bf16* __restrict__ WvT, bf16* __restrict__ qkbf, bf16* __restrict__ vTbf,
          const float* __restrict__ biasqk, const float* __restrict__ bv,
          float* __restrict__ S0, float* __restrict__ S1,
          const float* __restrict__ ent, const float* __restrict__ tabs,
          bf16* __restrict__ Pbuf, float* __restrict__ out,
          float* __restrict__ psum, float* __restrict__ psq,
          const float* __restrict__ g2, const float* __restrict__ b2,
          unsigned* __restrict__ barctr)
{
    __shared__ char smem[24576];
    const unsigned bid = blockIdx.x;
    const int tid = threadIdx.x;
    const unsigned NB = gridDim.x;

    // ---- P0: qk GEMM (512 tiles 128x64) + vT GEMM (256 tiles, even blocks) --
    gemm_12864<0>(featbf, 1024, WqkT, 1024, qkbf, 2048, 1024,
                  (int)(bid & 15) * 128, (int)(bid >> 4) * 64, biasqk, smem);
    if ((bid & 1) == 0) {
        const int j = bid >> 1;               // 0..255
        const int img = j >> 6, rem = j & 63; // 8m x 8n per img
        gemm_12864<1>(WvT, 1024, featbf + (long)img * 524288, 1024,
                      vTbf + (long)img * 524288, 512, 1024,
                      (rem >> 3) * 128, (rem & 7) * 64, bv, smem);
    }
    gridbar(barctr + 0, NB);

    // ---- P1: attn S tiles (512 items) --------------------------------------
    attn_body(qkbf, S0, S1, ent, tabs, bid & 7, (bid >> 3) & 7, bid >> 6, smem);
    gridbar(barctr + 1, NB);

    // ---- P2: softmax over S0+S1 (4 rows per block) -------------------------
    {
        __shared__ float redm[4], reds[4];
        for (int i = 0; i < 4; ++i) {
            const long row = (long)bid * 4 + i;
            float x0 = S0[row * 512 + tid]       + S1[row * 512 + tid];
            float x1 = S0[row * 512 + tid + 256] + S1[row * 512 + tid + 256];
            float mx = fmaxf(x0, x1);
#pragma unroll
            for (int off = 32; off; off >>= 1) mx = fmaxf(mx, __shfl_xor(mx, off));
            if ((tid & 63) == 0) redm[tid >> 6] = mx;
            __syncthreads();
            mx = fmaxf(fmaxf(redm[0], redm[1]), fmaxf(redm[2], redm[3]));
            float e0 = __expf(x0 - mx), e1 = __expf(x1 - mx);
            float sm = e0 + e1;
#pragma unroll
            for (int off = 32; off; off >>= 1) sm += __shfl_xor(sm, off);
            if ((tid & 63) == 0) reds[tid >> 6] = sm;
            __syncthreads();
            sm = (reds[0] + reds[1]) + (reds[2] + reds[3]);
            float inv = 1.0f / sm;
            Pbuf[row * 512 + tid]       = (bf16)(e0 * inv);
            Pbuf[row * 512 + tid + 256] = (bf16)(e1 * inv);
            __syncthreads();
        }
    }
    gridbar(barctr + 2, NB);

    // ---- P3: pv GEMM + bn2 stats (512 items) -------------------------------
    pv_body(Pbuf, vTbf, out, psum, psq, (bid >> 4) & 7, bid & 15, bid >> 7, smem);
    gridbar(barctr + 3, NB);

    // ---- P4: bn2 finalize + apply (512 items: 16 stripes x 32 chunks) ------
    {
        __shared__ float ls[4][64], lq[4][64], ssc[64], ssh[64];
        const int cs = bid & 15, rc = bid >> 4;
        const int col_l = tid & 63, part = tid >> 6;
        const int col = cs * 64 + col_l;
        float s = 0.f, q = 0.f;
#pragma unroll
        for (int i = 0; i < 8; ++i) {
            int ch = part * 8 + i;
            s += psum[ch * 1024 + col];
            q += psq [ch * 1024 + col];
        }
        ls[part][col_l] = s; lq[part][col_l] = q;
        __syncthreads();
        if (tid < 64) {
            float S = ls[0][tid]+ls[1][tid]+ls[2][tid]+ls[3][tid];
            float Q = lq[0][tid]+lq[1][tid]+lq[2][tid]+lq[3][tid];
            float m = S / 2048.f;
            float v = Q / 2048.f - m*m;
            float inv = 1.0f / sqrtf(v + 1e-5f);
            float sc = g2[cs*64+tid] * inv;
            ssc[tid] = sc; ssh[tid] = b2[cs*64+tid] - m*sc;
        }
        __syncthreads();
        const int f = tid & 15, rsub = tid >> 4;
        float4 sc4 = ((const float4*)ssc)[f];
        float4 sh4 = ((const float4*)ssh)[f];
#pragma unroll
        for (int it = 0; it < 4; ++it) {
            int row = rc*64 + it*16 + rsub;
            float4 x = ((const float4*)(out + (long)row*1024 + cs*64))[f];
            float4 rv;
            rv.x = x.x*sc4.x + sh4.x;
            rv.y = x.y*sc4.y + sh4.y;
            rv.z = x.z*sc4.z + sh4.z;
            rv.w = x.w*sc4.w + sh4.w;
            ((float4*)(out + (long)row*1024 + cs*64))[f] = rv;
        }
    }
}

// ---------------------------------------------------------------------------
extern "C" void kernel_launch(void* const* d_in, const int* in_sizes, int n_in,
                              void* d_out, int out_size, void* d_ws, size_t ws_size,
                              hipStream_t stream)
{
    const float* box_features = (const float*)d_in[0];
    const float* boxes  = (const float*)d_in[1];
    const float* bn1_g  = (const float*)d_in[2];
    const float* bn1_b  = (const float*)d_in[3];
    const float* Wq     = (const float*)d_in[4];
    const float* bq     = (const float*)d_in[5];
    const float* Wk     = (const float*)d_in[6];
    const float* bk     = (const float*)d_in[7];
    const float* Wv     = (const float*)d_in[8];
    const float* bv     = (const float*)d_in[9];
    const float* Wr     = (const float*)d_in[10];
    const float* br     = (const float*)d_in[11];
    const float* bn2_g  = (const float*)d_in[12];
    const float* bn2_b  = (const float*)d_in[13];
    float* out = (float*)d_out;

    char* ws = (char*)d_ws;
    const long MB = 1024 * 1024;
    float*    psum   = (float*)(ws + 0);                 // 128x1024 f32
    float*    psq    = (float*)(ws + 512 * 1024);
    float*    biasqk = (float*)(ws + 1 * MB);            // 2048 f32
    float*    ent    = (float*)(ws + 1 * MB + 65536);    // 6 x 2048 f32
    float*    tabs   = (float*)(ws + 1 * MB + 131072);   // 4096 f32
    unsigned* barctr = (unsigned*)(ws + 1 * MB + 163840);// 8 u32
    bf16*     featbf = (bf16*)(ws + 2 * MB);             // 2048x1024 bf16 (4MB)
    bf16*     WqkT   = (bf16*)(ws + 6 * MB);             // 2048x1024 bf16 (4MB)
    float*    Sbuf1  = (float*)(ws + 6 * MB);            // aliases WqkT (dead after P0; barrier separates)
    bf16*     WvT    = (bf16*)(ws + 10 * MB);            // 1024x1024 bf16 (2MB)
    bf16*     qkbf   = (bf16*)(ws + 12 * MB);            // 2048x2048 bf16 (8MB)
    bf16*     vTbf   = (bf16*)(ws + 20 * MB);            // 4x1024x512 bf16 (4MB)
    float*    Sbuf0  = (float*)(ws + 24 * MB);           // 4x512x512 f32 (4MB)
    bf16*     Pbuf   = (bf16*)(ws + 28 * MB);            // 4x512x512 bf16 (2MB)

    prep<<<dim3(901, 1, 1), dim3(256, 1, 1), 0, stream>>>(
        Wq, Wk, Wv, WqkT, WqkT + 1024 * 1024, WvT, bq, bk, biasqk,
        box_features, psum, psq, boxes, Wr, br, ent, tabs, barctr);

    bn1_final_apply<<<dim3(16, 16, 1), dim3(256, 1, 1), 0, stream>>>(
        box_features, psum, psq, bn1_g, bn1_b, featbf);

    mega<<<dim3(512, 1, 1), dim3(256, 1, 1), 0, stream>>>(
        featbf, WqkT, WvT, qkbf, vTbf, biasqk, bv,
        Sbuf0, Sbuf1, ent, tabs, Pbuf, out, psum, psq, bn2_g, bn2_b, barctr);
}

// Round 11
// 239.367 us; speedup vs baseline: 2.4182x; 2.4182x over previous
//
#include <hip/hip_runtime.h>
#include <math.h>

typedef __bf16 bf16;
typedef __attribute__((ext_vector_type(8))) __bf16 bf16x8;
typedef __attribute__((ext_vector_type(4))) __bf16 bf16x4;
typedef __attribute__((ext_vector_type(4))) float f32x4;

#define NCH1 128
#define RPC1 16

#define XD0   (-6.93f)
#define XSPAN (11.03f)
#define XINVH (1023.f / 11.03f)

// ---------------------------------------------------------------------------
// prep mega-kernel: 901 blocks (also zeroes grid-barrier counters)
// ---------------------------------------------------------------------------
__global__ __launch_bounds__(256)
void prep(const float* __restrict__ Wq, const float* __restrict__ Wk, const float* __restrict__ Wv,
          bf16* __restrict__ T0, bf16* __restrict__ T1, bf16* __restrict__ T2,
          const float* __restrict__ bq, const float* __restrict__ bk, float* __restrict__ biasqk,
          const float* __restrict__ X, float* __restrict__ psum, float* __restrict__ psq,
          const float* __restrict__ boxes, const float* __restrict__ Wr, const float* __restrict__ br,
          float* __restrict__ ent, float* __restrict__ tabs, unsigned* __restrict__ barctr)
{
    __shared__ float tile[64][65];
    const int bid = blockIdx.x;
    const int tid = threadIdx.x;

    if (bid < 768) {
        const int mat = bid >> 8, g2 = bid & 255;
        const float* W = (mat == 0) ? Wq : (mat == 1) ? Wk : Wv;
        bf16* T        = (mat == 0) ? T0 : (mat == 1) ? T1 : T2;
        const int bx = (g2 & 15) * 64, by = (g2 >> 4) * 64;
        const int tx = tid & 63, ty = tid >> 6;
#pragma unroll
        for (int i = 0; i < 16; ++i)
            tile[ty + i * 4][tx] = W[(long)(by + ty + i * 4) * 1024 + bx + tx];
        __syncthreads();
#pragma unroll
        for (int i = 0; i < 16; ++i)
            T[(long)(bx + ty + i * 4) * 1024 + by + tx] = (bf16)tile[tx][ty + i * 4];
    } else if (bid < 896) {
        const int c4 = tid;
        const long r0 = (long)(bid - 768) * RPC1;
        const float4* Xv = (const float4*)X;
        float4 s = {0.f,0.f,0.f,0.f}, q = {0.f,0.f,0.f,0.f};
#pragma unroll
        for (int r = 0; r < RPC1; ++r) {
            float4 x = Xv[(r0 + r) * 256 + c4];
            s.x += x.x; s.y += x.y; s.z += x.z; s.w += x.w;
            q.x += x.x*x.x; q.y += x.y*x.y; q.z += x.z*x.z; q.w += x.w*x.w;
        }
        ((float4*)psum)[(bid - 768) * 256 + c4] = s;
        ((float4*)psq) [(bid - 768) * 256 + c4] = q;
    } else if (bid == 896) {
        for (int e = tid; e < 2048; e += 256) {
            float4 b4 = ((const float4*)boxes)[e];
            float w = b4.z, h = b4.w;
            ent[0*2048+e] = b4.x + 0.5f * w;
            ent[1*2048+e] = b4.y + 0.5f * h;
            ent[2*2048+e] = __logf(w);
            ent[3*2048+e] = __logf(h);
            ent[4*2048+e] = 1e-3f * w;
            ent[5*2048+e] = 1e-3f * h;
        }
        for (int i = tid; i < 2048; i += 256)
            biasqk[i] = (i < 1024) ? bq[i] : bk[i - 1024];
        if (tid < 8) barctr[tid] = 0u;
        __threadfence();
    } else {
        const int c = bid - 897;
        float* tb = tabs + c * 1024;
        const float brq = 0.25f * br[0];
        const float hstep = XSPAN / 1023.f;
        for (int e = tid; e < 1024; e += 256) {
            float d = XD0 + hstep * (float)e;
            float a = brq;
#pragma unroll
            for (int k = 0; k < 16; ++k) {
                float tk = exp2f(-1.24572303558f * (float)k);
                float s_, c_;
                __sincosf(d * tk, &s_, &c_);
                a += s_ * Wr[c * 32 + k] + c_ * Wr[c * 32 + 16 + k];
            }
            tb[e] = a;
        }
    }
}

// ------- bn1: finalize stats (per 64-col stripe) + apply -> bf16 ------------
__global__ __launch_bounds__(256)
void bn1_final_apply(const float* __restrict__ X, const float* __restrict__ psum,
                     const float* __restrict__ psq, const float* __restrict__ g,
                     const float* __restrict__ b, bf16* __restrict__ Yp)
{
    __shared__ float ls[4][64], lq[4][64], ssc[64], ssh[64];
    const int t  = threadIdx.x;
    const int cs = blockIdx.x;
    const int rc = blockIdx.y;
    const int col_l = t & 63, part = t >> 6;
    const int col = cs * 64 + col_l;
    float s = 0.f, q = 0.f;
#pragma unroll
    for (int i = 0; i < 32; ++i) {
        int ch = part * 32 + i;
        s += psum[ch * 1024 + col];
        q += psq [ch * 1024 + col];
    }
    ls[part][col_l] = s; lq[part][col_l] = q;
    __syncthreads();
    if (t < 64) {
        float S = ls[0][t]+ls[1][t]+ls[2][t]+ls[3][t];
        float Q = lq[0][t]+lq[1][t]+lq[2][t]+lq[3][t];
        float m = S / 2048.f;
        float v = Q / 2048.f - m*m;
        float inv = 1.0f / sqrtf(v + 1e-5f);
        float sc = g[cs*64+t] * inv;
        ssc[t] = sc; ssh[t] = b[cs*64+t] - m*sc;
    }
    __syncthreads();
    const int f = t & 15, rsub = t >> 4;
    float4 sc4 = ((const float4*)ssc)[f];
    float4 sh4 = ((const float4*)ssh)[f];
#pragma unroll
    for (int it = 0; it < 8; ++it) {
        int row = rc*128 + it*16 + rsub;
        float4 x = ((const float4*)(X + (long)row*1024 + cs*64))[f];
        bf16x4 y;
        y[0]=(bf16)(x.x*sc4.x + sh4.x);
        y[1]=(bf16)(x.y*sc4.y + sh4.y);
        y[2]=(bf16)(x.z*sc4.z + sh4.z);
        y[3]=(bf16)(x.w*sc4.w + sh4.w);
        ((bf16x4*)(Yp + (long)row*1024 + cs*64))[f] = y;
    }
}

// ---------------- rel table lookup ------------------------------------------
__device__ __forceinline__ float look(const float* tab, float d)
{
    float t = (d - XD0) * XINVH;
    t = fminf(fmaxf(t, 0.f), 1022.999f);
    float fi = floorf(t);
    int i = (int)fi;
    float a = tab[i], b = tab[i + 1];
    return a + (b - a) * (t - fi);
}

// ---------------- staging helpers -------------------------------------------
__device__ __forceinline__ void stage_tile_128x32(const bf16* __restrict__ src_base, int ld,
                                                  int row0, int k0, bf16* lds_base, int w, int l)
{
#pragma unroll
    for (int t = 0; t < 2; ++t) {
        int rchunk = w * 32 + t * 16;
        const bf16* src = src_base + (long)(row0 + rchunk + (l >> 2)) * ld + k0 + (l & 3) * 8;
        __builtin_amdgcn_global_load_lds((__attribute__((address_space(1))) void*)src,
                                         (__attribute__((address_space(3))) void*)(lds_base + rchunk * 32),
                                         16, 0, 0);
    }
}

__device__ __forceinline__ void stage64(const bf16* __restrict__ src_base, int ld,
                                        int row0, int k0, bf16* lds_base, int w, int l)
{
    const bf16* src = src_base + (long)(row0 + w * 16 + (l >> 2)) * ld + k0 + (l & 3) * 8;
    __builtin_amdgcn_global_load_lds((__attribute__((address_space(1))) void*)src,
                                     (__attribute__((address_space(3))) void*)(lds_base + w * 16 * 32),
                                     16, 0, 0);
}

// ---------------- 128x128 MFMA GEMM body (R6-proven) ------------------------
// MODE 0: bf16 out +bias[col]    1: bf16 out +bias[row]
template <int MODE>
__device__ __forceinline__ void gemm_body(
    const bf16* __restrict__ Ab, int lda, const bf16* __restrict__ Bb, int ldb,
    bf16* __restrict__ Cp, int ldc, int K, int bm, int bn,
    const float* __restrict__ bias, char* smem)
{
    bf16* As0 = (bf16*)smem;
    bf16* Bs0 = (bf16*)(smem + 16384);
    const int tid = threadIdx.x;
    const int w = tid >> 6, l = tid & 63;
    const int wr = w >> 1, wc = w & 1;

    f32x4 acc[4][4];
#pragma unroll
    for (int i = 0; i < 4; ++i)
#pragma unroll
        for (int j = 0; j < 4; ++j) acc[i][j] = (f32x4){0.f,0.f,0.f,0.f};

    const int nkt = K >> 5;
    stage_tile_128x32(Ab, lda, bm, 0, As0, w, l);
    stage_tile_128x32(Bb, ldb, bn, 0, Bs0, w, l);
    __syncthreads();

    const int fr = l & 15;
    const int ko = (l >> 4) * 8;

    for (int kt = 0; kt < nkt; ++kt) {
        const int cur = kt & 1;
        bf16* Asc = As0 + cur * 4096;
        bf16* Bsc = Bs0 + cur * 4096;
        if (kt + 1 < nkt) {
            stage_tile_128x32(Ab, lda, bm, (kt + 1) << 5, As0 + (cur ^ 1) * 4096, w, l);
            stage_tile_128x32(Bb, ldb, bn, (kt + 1) << 5, Bs0 + (cur ^ 1) * 4096, w, l);
        }
        bf16x8 af[4], bfv[4];
#pragma unroll
        for (int mi = 0; mi < 4; ++mi)
            af[mi] = *(const bf16x8*)(&Asc[(wr * 64 + mi * 16 + fr) * 32 + ko]);
#pragma unroll
        for (int ni = 0; ni < 4; ++ni)
            bfv[ni] = *(const bf16x8*)(&Bsc[(wc * 64 + ni * 16 + fr) * 32 + ko]);
#pragma unroll
        for (int mi = 0; mi < 4; ++mi)
#pragma unroll
            for (int ni = 0; ni < 4; ++ni)
                acc[mi][ni] = __builtin_amdgcn_mfma_f32_16x16x32_bf16(af[mi], bfv[ni], acc[mi][ni], 0, 0, 0);
        __syncthreads();
    }

    const int crow0 = bm + wr * 64 + (l >> 4) * 4;
    const int ccol0 = bn + wc * 64 + fr;
#pragma unroll
    for (int mi = 0; mi < 4; ++mi)
#pragma unroll
        for (int ni = 0; ni < 4; ++ni)
#pragma unroll
            for (int r = 0; r < 4; ++r) {
                const int row = crow0 + mi * 16 + r;
                const int col = ccol0 + ni * 16;
                const float v = acc[mi][ni][r];
                if constexpr (MODE == 0) {
                    Cp[(long)row * ldc + col] = (bf16)(v + bias[col]);
                } else {
                    Cp[(long)row * ldc + col] = (bf16)(v + bias[row]);
                }
            }
}

// --------- megaGEMM: qk (256 tiles 128^2) + vT (128 tiles 128^2), R6-exact --
__global__ __launch_bounds__(256, 2)
void megaGEMM(const bf16* __restrict__ featbf, const bf16* __restrict__ WqkT,
              const bf16* __restrict__ WvT, bf16* __restrict__ qkbf, bf16* __restrict__ vTbf,
              const float* __restrict__ biasqk, const float* __restrict__ bv)
{
    __shared__ char smem[32768];
    const unsigned bid = blockIdx.x;
    const unsigned g = bid / 3u, r = bid % 3u;
    if (r < 2) {
        const unsigned t = g * 2 + r;
        gemm_body<0>(featbf, 1024, WqkT, 1024, qkbf, 2048, 1024,
                     (t & 15) * 128, (t >> 4) * 128, biasqk, smem);
    } else {
        const int img = g >> 5, rem = g & 31;
        gemm_body<1>(WvT, 1024, featbf + (long)img * 524288, 1024,
                     vTbf + (long)img * 524288, 512, 1024,
                     (rem >> 2) * 128, (rem & 3) * 128, bv, smem);
    }
}

// ---------------- attn body (R6-proven, verbatim) ---------------------------
__device__ __forceinline__ void attn_body(
    const bf16* __restrict__ qk, float* __restrict__ S0, float* __restrict__ S1,
    const float* __restrict__ ent, const float* __restrict__ tabs,
    int bx, int by, int bz, char* smem)
{
    const int img = bz >> 1, kh = bz & 1;
    const int bm = bx * 64, bn = by * 64;
    const bf16* A = qk + (long)img * 1048576 + kh * 512;
    const bf16* B = qk + 1024 + (long)img * 1048576 + kh * 512;
    bf16* As0 = (bf16*)smem;
    bf16* Bs0 = (bf16*)(smem + 8192);

    const int tid = threadIdx.x;
    const int w = tid >> 6, l = tid & 63;
    const int wr = w >> 1, wc = w & 1;
    const int fr = l & 15;
    const int ko = (l >> 4) * 8;

    f32x4 acc[2][2];
#pragma unroll
    for (int i = 0; i < 2; ++i)
#pragma unroll
        for (int j = 0; j < 2; ++j) acc[i][j] = (f32x4){0.f,0.f,0.f,0.f};

    stage64(A, 2048, bm, 0, As0, w, l);
    stage64(B, 2048, bn, 0, Bs0, w, l);
    __syncthreads();

    for (int kt = 0; kt < 16; ++kt) {
        const int cur = kt & 1;
        bf16* Asc = As0 + cur * 2048;
        bf16* Bsc = Bs0 + cur * 2048;
        if (kt + 1 < 16) {
            stage64(A, 2048, bm, (kt + 1) << 5, As0 + (cur ^ 1) * 2048, w, l);
            stage64(B, 2048, bn, (kt + 1) << 5, Bs0 + (cur ^ 1) * 2048, w, l);
        }
        bf16x8 af[2], bfv[2];
#pragma unroll
        for (int mi = 0; mi < 2; ++mi)
            af[mi] = *(const bf16x8*)(&Asc[(wr * 32 + mi * 16 + fr) * 32 + ko]);
#pragma unroll
        for (int ni = 0; ni < 2; ++ni)
            bfv[ni] = *(const bf16x8*)(&Bsc[(wc * 32 + ni * 16 + fr) * 32 + ko]);
#pragma unroll
        for (int mi = 0; mi < 2; ++mi)
#pragma unroll
            for (int ni = 0; ni < 2; ++ni)
                acc[mi][ni] = __builtin_amdgcn_mfma_f32_16x16x32_bf16(af[mi], bfv[ni], acc[mi][ni], 0, 0, 0);
        __syncthreads();
    }

    const float scale = 0.03125f;
    float* Sout = (kh == 0 ? S0 : S1) + (long)img * 262144;

    if (kh == 1) {
#pragma unroll
        for (int mi = 0; mi < 2; ++mi)
#pragma unroll
            for (int ni = 0; ni < 2; ++ni)
#pragma unroll
                for (int r = 0; r < 4; ++r) {
                    const int rowl = wr * 32 + mi * 16 + (l >> 4) * 4 + r;
                    const int coll = wc * 32 + ni * 16 + fr;
                    Sout[(long)(bm + rowl) * 512 + bn + coll] = acc[mi][ni][r] * scale;
                }
        return;
    }

    float* stab = (float*)smem;
    float* RA   = stab + 4096;
    float* SA   = RA + 64;
    float* SE   = SA + 260;
    float* SL   = SE + 260;
    const int b   = bn >> 7;
    const int jj0 = (bn & 64) * 4;
    for (int i = tid; i < 4096; i += 256) stab[i] = tabs[i];
    {
        const int eb = img * 512;
        if (tid < 64) RA[tid] = ent[b * 2048 + eb + bm + tid];
        for (int u = tid; u < 260 && jj0 + u < 512; u += 256) {
            SA[u] = ent[b * 2048 + eb + jj0 + u];
            if (b < 2) {
                SE[u] = ent[(4 + b) * 2048 + eb + jj0 + u];
                SL[u] = ent[(2 + b) * 2048 + eb + jj0 + u];
            }
        }
    }
    __syncthreads();
#pragma unroll
    for (int ni = 0; ni < 2; ++ni) {
        const int coll = wc * 32 + ni * 16 + fr;
        const int u0   = 4 * coll;
        const float sA0 = SA[u0], sA1 = SA[u0+1], sA2 = SA[u0+2], sA3 = SA[u0+3];
        float sE0=0.f,sE1=0.f,sE2=0.f,sE3=0.f, sL0=0.f,sL1=0.f,sL2=0.f,sL3=0.f;
        if (b < 2) {
            sE0 = SE[u0]; sE1 = SE[u0+1]; sE2 = SE[u0+2]; sE3 = SE[u0+3];
            sL0 = SL[u0]; sL1 = SL[u0+1]; sL2 = SL[u0+2]; sL3 = SL[u0+3];
        }
#pragma unroll
        for (int mi = 0; mi < 2; ++mi)
#pragma unroll
            for (int r = 0; r < 4; ++r) {
                const int rowl = wr * 32 + mi * 16 + (l >> 4) * 4 + r;
                const float ai = RA[rowl];
                float d0, d1, d2, d3;
                if (b < 2) {
                    d0 = __logf(fmaxf(fabsf(ai - sA0), sE0)) - sL0;
                    d1 = __logf(fmaxf(fabsf(ai - sA1), sE1)) - sL1;
                    d2 = __logf(fmaxf(fabsf(ai - sA2), sE2)) - sL2;
                    d3 = __logf(fmaxf(fabsf(ai - sA3), sE3)) - sL3;
                } else {
                    d0 = ai - sA0; d1 = ai - sA1; d2 = ai - sA2; d3 = ai - sA3;
                }
                float relv = look(stab,        d0) + look(stab + 1024, d1)
                           + look(stab + 2048, d2) + look(stab + 3072, d3);
                Sout[(long)(bm + rowl) * 512 + bn + coll] = acc[mi][ni][r] * scale + relv;
            }
    }
}

// ---------------- pv body (R6-proven, verbatim) -----------------------------
__device__ __forceinline__ void pv_body(
    const bf16* __restrict__ P, const bf16* __restrict__ vT, float* __restrict__ out,
    float* __restrict__ psum, float* __restrict__ psq,
    int mt, int nt, int img, char* smem)
{
    const int bm = mt * 64, bn = nt * 64;
    const bf16* A = P  + (long)img * 262144;
    const bf16* B = vT + (long)img * 524288;
    float* C = out + (long)img * 524288;
    bf16* As0 = (bf16*)smem;
    bf16* Bs0 = (bf16*)(smem + 8192);

    const int tid = threadIdx.x;
    const int w = tid >> 6, l = tid & 63;
    const int wr = w >> 1, wc = w & 1;
    const int fr = l & 15;
    const int ko = (l >> 4) * 8;

    f32x4 acc[2][2];
#pragma unroll
    for (int i = 0; i < 2; ++i)
#pragma unroll
        for (int j = 0; j < 2; ++j) acc[i][j] = (f32x4){0.f,0.f,0.f,0.f};

    stage64(A, 512, bm, 0, As0, w, l);
    stage64(B, 512, bn, 0, Bs0, w, l);
    __syncthreads();

    for (int kt = 0; kt < 16; ++kt) {
        const int cur = kt & 1;
        bf16* Asc = As0 + cur * 2048;
        bf16* Bsc = Bs0 + cur * 2048;
        if (kt + 1 < 16) {
            stage64(A, 512, bm, (kt + 1) << 5, As0 + (cur ^ 1) * 2048, w, l);
            stage64(B, 512, bn, (kt + 1) << 5, Bs0 + (cur ^ 1) * 2048, w, l);
        }
        bf16x8 af[2], bfv[2];
#pragma unroll
        for (int mi = 0; mi < 2; ++mi)
            af[mi] = *(const bf16x8*)(&Asc[(wr * 32 + mi * 16 + fr) * 32 + ko]);
#pragma unroll
        for (int ni = 0; ni < 2; ++ni)
            bfv[ni] = *(const bf16x8*)(&Bsc[(wc * 32 + ni * 16 + fr) * 32 + ko]);
#pragma unroll
        for (int mi = 0; mi < 2; ++mi)
#pragma unroll
            for (int ni = 0; ni < 2; ++ni)
                acc[mi][ni] = __builtin_amdgcn_mfma_f32_16x16x32_bf16(af[mi], bfv[ni], acc[mi][ni], 0, 0, 0);
        __syncthreads();
    }

#pragma unroll
    for (int mi = 0; mi < 2; ++mi)
#pragma unroll
        for (int ni = 0; ni < 2; ++ni)
#pragma unroll
            for (int r = 0; r < 4; ++r) {
                const int rowl = wr * 32 + mi * 16 + (l >> 4) * 4 + r;
                const int coll = wc * 32 + ni * 16 + fr;
                C[(long)(bm + rowl) * 1024 + bn + coll] = acc[mi][ni][r];
            }

    float s_[2], q_[2];
#pragma unroll
    for (int ni = 0; ni < 2; ++ni) {
        float s = 0.f, q = 0.f;
#pragma unroll
        for (int mi = 0; mi < 2; ++mi)
#pragma unroll
            for (int r = 0; r < 4; ++r) { float v = acc[mi][ni][r]; s += v; q += v * v; }
        s_[ni] = s; q_[ni] = q;
    }
#pragma unroll
    for (int ni = 0; ni < 2; ++ni) {
        s_[ni] += __shfl_xor(s_[ni], 16); s_[ni] += __shfl_xor(s_[ni], 32);
        q_[ni] += __shfl_xor(q_[ni], 16); q_[ni] += __shfl_xor(q_[ni], 32);
    }
    float* lred = (float*)smem;
    __syncthreads();
    if (l < 16) {
#pragma unroll
        for (int ni = 0; ni < 2; ++ni) {
            const int c = wc * 32 + ni * 16 + l;
            lred[(wr * 2 + 0) * 64 + c] = s_[ni];
            lred[(wr * 2 + 1) * 64 + c] = q_[ni];
        }
    }
    __syncthreads();
    if (tid < 64) {
        const int chunk = img * 8 + mt;
        psum[chunk * 1024 + bn + tid] = lred[0 * 64 + tid] + lred[2 * 64 + tid];
        psq [chunk * 1024 + bn + tid] = lred[1 * 64 + tid] + lred[3 * 64 + tid];
    }
}

// ---------------- grid barrier: RMW-poll (no per-iteration cache inv) -------
__device__ __forceinline__ void gridbar(unsigned* __restrict__ ctr, unsigned target)
{
    __syncthreads();
    if (threadIdx.x == 0) {
        __threadfence();                       // release: L2 writeback (covers whole XCD)
        atomicAdd(ctr, 1u);
        while (atomicAdd(ctr, 0u) < target)    // coherent RMW poll, no cache invalidation
            __builtin_amdgcn_s_sleep(4);
        __threadfence();                       // acquire: invalidate before reading others' data
    }
    __syncthreads();
}

// ---------------- persistent tail: attn -> softmax -> pv -> bn2 -------------
// 512 blocks, 2/CU co-resident; every phase is exactly 1 balanced item/block.
__global__ __launch_bounds__(256, 2)
void tail(const bf16* __restrict__ qkbf, float* __restrict__ S0, float* __restrict__ S1,
          const float* __restrict__ ent, const float* __restrict__ tabs,
          bf16* __restrict__ Pbuf, const bf16* __restrict__ vTbf, float* __restrict__ out,
          float* __restrict__ psum, float* __restrict__ psq,
          const float* __restrict__ g2, const float* __restrict__ b2,
          unsigned* __restrict__ barctr)
{
    __shared__ char smem[20480];
    const unsigned bid = blockIdx.x;
    const int tid = threadIdx.x;
    const unsigned NB = gridDim.x;

    // P1: attn S tiles (512 items)
    attn_body(qkbf, S0, S1, ent, tabs, bid & 7, (bid >> 3) & 7, bid >> 6, smem);
    gridbar(barctr + 0, NB);

    // P2: softmax over S0+S1 (4 rows per block)
    {
        __shared__ float redm[4], reds[4];
        for (int i = 0; i < 4; ++i) {
            const long row = (long)bid * 4 + i;
            float x0 = S0[row * 512 + tid]       + S1[row * 512 + tid];
            float x1 = S0[row * 512 + tid + 256] + S1[row * 512 + tid + 256];
            float mx = fmaxf(x0, x1);
#pragma unroll
            for (int off = 32; off; off >>= 1) mx = fmaxf(mx, __shfl_xor(mx, off));
            if ((tid & 63) == 0) redm[tid >> 6] = mx;
            __syncthreads();
            mx = fmaxf(fmaxf(redm[0], redm[1]), fmaxf(redm[2], redm[3]));
            float e0 = __expf(x0 - mx), e1 = __expf(x1 - mx);
            float sm = e0 + e1;
#pragma unroll
            for (int off = 32; off; off >>= 1) sm += __shfl_xor(sm, off);
            if ((tid & 63) == 0) reds[tid >> 6] = sm;
            __syncthreads();
            sm = (reds[0] + reds[1]) + (reds[2] + reds[3]);
            float inv = 1.0f / sm;
            Pbuf[row * 512 + tid]       = (bf16)(e0 * inv);
            Pbuf[row * 512 + tid + 256] = (bf16)(e1 * inv);
            __syncthreads();
        }
    }
    gridbar(barctr + 1, NB);

    // P3: pv GEMM + bn2 stats (512 items)
    pv_body(Pbuf, vTbf, out, psum, psq, (bid >> 4) & 7, bid & 15, bid >> 7, smem);
    gridbar(barctr + 2, NB);

    // P4: bn2 finalize + apply (512 items: 16 col-stripes x 32 row-chunks)
    {
        __shared__ float ls[4][64], lq[4][64], ssc[64], ssh[64];
        const int cs = bid & 15, rc = bid >> 4;
        const int col_l = tid & 63, part = tid >> 6;
        const int col = cs * 64 + col_l;
        float s = 0.f, q = 0.f;
#pragma unroll
        for (int i = 0; i < 8; ++i) {
            int ch = part * 8 + i;
            s += psum[ch * 1024 + col];
            q += psq [ch * 1024 + col];
        }
        ls[part][col_l] = s; lq[part][col_l] = q;
        __syncthreads();
        if (tid < 64) {
            float S = ls[0][tid]+ls[1][tid]+ls[2][tid]+ls[3][tid];
            float Q = lq[0][tid]+lq[1][tid]+lq[2][tid]+lq[3][tid];
            float m = S / 2048.f;
            float v = Q / 2048.f - m*m;
            float inv = 1.0f / sqrtf(v + 1e-5f);
            float sc = g2[cs*64+tid] * inv;
            ssc[tid] = sc; ssh[tid] = b2[cs*64+tid] - m*sc;
        }
        __syncthreads();
        const int f = tid & 15, rsub = tid >> 4;
        float4 sc4 = ((const float4*)ssc)[f];
        float4 sh4 = ((const float4*)ssh)[f];
#pragma unroll
        for (int it = 0; it < 4; ++it) {
            int row = rc*64 + it*16 + rsub;
            float4 x = ((const float4*)(out + (long)row*1024 + cs*64))[f];
            float4 rv;
            rv.x = x.x*sc4.x + sh4.x;
            rv.y = x.y*sc4.y + sh4.y;
            rv.z = x.z*sc4.z + sh4.z;
            rv.w = x.w*sc4.w + sh4.w;
            ((float4*)(out + (long)row*1024 + cs*64))[f] = rv;
        }
    }
}

// ---------------------------------------------------------------------------
extern "C" void kernel_launch(void* const* d_in, const int* in_sizes, int n_in,
                              void* d_out, int out_size, void* d_ws, size_t ws_size,
                              hipStream_t stream)
{
    const float* box_features = (const float*)d_in[0];
    const float* boxes  = (const float*)d_in[1];
    const float* bn1_g  = (const float*)d_in[2];
    const float* bn1_b  = (const float*)d_in[3];
    const float* Wq     = (const float*)d_in[4];
    const float* bq     = (const float*)d_in[5];
    const float* Wk     = (const float*)d_in[6];
    const float* bk     = (const float*)d_in[7];
    const float* Wv     = (const float*)d_in[8];
    const float* bv     = (const float*)d_in[9];
    const float* Wr     = (const float*)d_in[10];
    const float* br     = (const float*)d_in[11];
    const float* bn2_g  = (const float*)d_in[12];
    const float* bn2_b  = (const float*)d_in[13];
    float* out = (float*)d_out;

    char* ws = (char*)d_ws;
    const long MB = 1024 * 1024;
    float*    psum   = (float*)(ws + 0);
    float*    psq    = (float*)(ws + 512 * 1024);
    float*    biasqk = (float*)(ws + 1 * MB);
    float*    ent    = (float*)(ws + 1 * MB + 65536);
    float*    tabs   = (float*)(ws + 1 * MB + 131072);
    unsigned* barctr = (unsigned*)(ws + 1 * MB + 163840);
    bf16*     featbf = (bf16*)(ws + 2 * MB);
    bf16*     WqkT   = (bf16*)(ws + 6 * MB);
    float*    Sbuf1  = (float*)(ws + 6 * MB);     // aliases WqkT (dead after megaGEMM)
    bf16*     WvT    = (bf16*)(ws + 10 * MB);
    bf16*     qkbf   = (bf16*)(ws + 12 * MB);
    bf16*     vTbf   = (bf16*)(ws + 20 * MB);
    float*    Sbuf0  = (float*)(ws + 24 * MB);
    bf16*     Pbuf   = (bf16*)(ws + 28 * MB);

    prep<<<dim3(901, 1, 1), dim3(256, 1, 1), 0, stream>>>(
        Wq, Wk, Wv, WqkT, WqkT + 1024 * 1024, WvT, bq, bk, biasqk,
        box_features, psum, psq, boxes, Wr, br, ent, tabs, barctr);

    bn1_final_apply<<<dim3(16, 16, 1), dim3(256, 1, 1), 0, stream>>>(
        box_features, psum, psq, bn1_g, bn1_b, featbf);

    megaGEMM<<<dim3(384, 1, 1), dim3(256, 1, 1), 0, stream>>>(
        featbf, WqkT, WvT, qkbf, vTbf, biasqk, bv);

    tail<<<dim3(512, 1, 1), dim3(256, 1, 1), 0, stream>>>(
        qkbf, Sbuf0, Sbuf1, ent, tabs, Pbuf, vTbf, out, psum, psq, bn2_g, bn2_b, barctr);
}

// Round 12
// 86.815 us; speedup vs baseline: 6.6674x; 2.7572x over previous
//
#include <hip/hip_runtime.h>
#include <math.h>

typedef __bf16 bf16;
typedef __attribute__((ext_vector_type(8))) __bf16 bf16x8;
typedef __attribute__((ext_vector_type(4))) __bf16 bf16x4;
typedef __attribute__((ext_vector_type(4))) float f32x4;

#define NCH1 128  // row chunks for bn1 stats
#define RPC1 16   // rows per chunk

// rel-PE table domain: covers ln(1e-3) .. ln(57.5) and dw/dh range
#define XD0   (-6.93f)
#define XSPAN (11.03f)
#define XINVH (1023.f / 11.03f)

// ---------------------------------------------------------------------------
// prep mega-kernel: 901 blocks
// ---------------------------------------------------------------------------
__global__ __launch_bounds__(256)
void prep(const float* __restrict__ Wq, const float* __restrict__ Wk, const float* __restrict__ Wv,
          bf16* __restrict__ T0, bf16* __restrict__ T1, bf16* __restrict__ T2,
          const float* __restrict__ bq, const float* __restrict__ bk, float* __restrict__ biasqk,
          const float* __restrict__ X, float* __restrict__ psum, float* __restrict__ psq,
          const float* __restrict__ boxes, const float* __restrict__ Wr, const float* __restrict__ br,
          float* __restrict__ ent, float* __restrict__ tabs)
{
    __shared__ float tile[64][65];
    const int bid = blockIdx.x;
    const int tid = threadIdx.x;

    if (bid < 768) {                       // ---- weight transpose+cvt
        const int mat = bid >> 8, g2 = bid & 255;
        const float* W = (mat == 0) ? Wq : (mat == 1) ? Wk : Wv;
        bf16* T        = (mat == 0) ? T0 : (mat == 1) ? T1 : T2;
        const int bx = (g2 & 15) * 64, by = (g2 >> 4) * 64;
        const int tx = tid & 63, ty = tid >> 6;
#pragma unroll
        for (int i = 0; i < 16; ++i)
            tile[ty + i * 4][tx] = W[(long)(by + ty + i * 4) * 1024 + bx + tx];
        __syncthreads();
#pragma unroll
        for (int i = 0; i < 16; ++i)
            T[(long)(bx + ty + i * 4) * 1024 + by + tx] = (bf16)tile[tx][ty + i * 4];
    } else if (bid < 896) {                // ---- bn1 colstats partial
        const int c4 = tid;
        const long r0 = (long)(bid - 768) * RPC1;
        const float4* Xv = (const float4*)X;
        float4 s = {0.f,0.f,0.f,0.f}, q = {0.f,0.f,0.f,0.f};
#pragma unroll
        for (int r = 0; r < RPC1; ++r) {
            float4 x = Xv[(r0 + r) * 256 + c4];
            s.x += x.x; s.y += x.y; s.z += x.z; s.w += x.w;
            q.x += x.x*x.x; q.y += x.y*x.y; q.z += x.z*x.z; q.w += x.w*x.w;
        }
        ((float4*)psum)[(bid - 768) * 256 + c4] = s;
        ((float4*)psq) [(bid - 768) * 256 + c4] = q;
    } else if (bid == 896) {               // ---- entity values + bias pack
        for (int e = tid; e < 2048; e += 256) {
            float4 b4 = ((const float4*)boxes)[e];
            float w = b4.z, h = b4.w;
            ent[0*2048+e] = b4.x + 0.5f * w;   // cx
            ent[1*2048+e] = b4.y + 0.5f * h;   // cy
            ent[2*2048+e] = __logf(w);         // lw
            ent[3*2048+e] = __logf(h);         // lh
            ent[4*2048+e] = 1e-3f * w;         // ew
            ent[5*2048+e] = 1e-3f * h;         // eh
        }
        for (int i = tid; i < 2048; i += 256)
            biasqk[i] = (i < 1024) ? bq[i] : bk[i - 1024];
    } else {                               // ---- rel tables per weight slot
        const int c = bid - 897;           // weight slot 0..3
        float* tb = tabs + c * 1024;
        const float brq = 0.25f * br[0];
        const float hstep = XSPAN / 1023.f;
        for (int e = tid; e < 1024; e += 256) {
            float d = XD0 + hstep * (float)e;
            float a = brq;
#pragma unroll
            for (int k = 0; k < 16; ++k) {
                float tk = exp2f(-1.24572303558f * (float)k);  // 1000^(-k/8)
                float s_, c_;
                __sincosf(d * tk, &s_, &c_);
                a += s_ * Wr[c * 32 + k] + c_ * Wr[c * 32 + 16 + k];
            }
            tb[e] = a;
        }
    }
}

// ------- fused: finalize stats (per 64-col stripe) + apply BN ---------------
template <int NCH_, int BF16OUT>
__global__ __launch_bounds__(256)
void bn_final_apply(const float* __restrict__ X, const float* __restrict__ psum,
                    const float* __restrict__ psq, const float* __restrict__ g,
                    const float* __restrict__ b, void* __restrict__ Yp)
{
    __shared__ float ls[4][64], lq[4][64], ssc[64], ssh[64];
    const int t  = threadIdx.x;
    const int cs = blockIdx.x;
    const int rc = blockIdx.y;
    const int col_l = t & 63, part = t >> 6;
    const int col = cs * 64 + col_l;
    constexpr int CPT = NCH_ / 4;
    float s = 0.f, q = 0.f;
#pragma unroll
    for (int i = 0; i < CPT; ++i) {
        int ch = part * CPT + i;
        s += psum[ch * 1024 + col];
        q += psq [ch * 1024 + col];
    }
    ls[part][col_l] = s; lq[part][col_l] = q;
    __syncthreads();
    if (t < 64) {
        float S = ls[0][t]+ls[1][t]+ls[2][t]+ls[3][t];
        float Q = lq[0][t]+lq[1][t]+lq[2][t]+lq[3][t];
        float m = S / 2048.f;
        float v = Q / 2048.f - m*m;
        float inv = 1.0f / sqrtf(v + 1e-5f);
        float sc = g[cs*64+t] * inv;
        ssc[t] = sc; ssh[t] = b[cs*64+t] - m*sc;
    }
    __syncthreads();
    const int f = t & 15, rsub = t >> 4;
    float4 sc4 = ((const float4*)ssc)[f];
    float4 sh4 = ((const float4*)ssh)[f];
#pragma unroll
    for (int it = 0; it < 8; ++it) {
        int row = rc*128 + it*16 + rsub;
        float4 x = ((const float4*)(X + (long)row*1024 + cs*64))[f];
        float4 rv;
        rv.x = x.x*sc4.x + sh4.x;
        rv.y = x.y*sc4.y + sh4.y;
        rv.z = x.z*sc4.z + sh4.z;
        rv.w = x.w*sc4.w + sh4.w;
        if constexpr (BF16OUT) {
            bf16x4 y;
            y[0]=(bf16)rv.x; y[1]=(bf16)rv.y; y[2]=(bf16)rv.z; y[3]=(bf16)rv.w;
            ((bf16x4*)((bf16*)Yp + (long)row*1024 + cs*64))[f] = y;
        } else {
            ((float4*)((float*)Yp + (long)row*1024 + cs*64))[f] = rv;
        }
    }
}

// ---------------- rel table lookup ------------------------------------------
__device__ __forceinline__ float look(const float* tab, float d)
{
    float t = (d - XD0) * XINVH;
    t = fminf(fmaxf(t, 0.f), 1022.999f);
    float fi = floorf(t);
    int i = (int)fi;
    float a = tab[i], b = tab[i + 1];
    return a + (b - a) * (t - fi);
}

// ---------------- staging helpers -------------------------------------------
__device__ __forceinline__ void stage_tile_128x32(const bf16* __restrict__ src_base, int ld,
                                                  int row0, int k0, bf16* lds_base, int w, int l)
{
#pragma unroll
    for (int t = 0; t < 2; ++t) {
        int rchunk = w * 32 + t * 16;
        const bf16* src = src_base + (long)(row0 + rchunk + (l >> 2)) * ld + k0 + (l & 3) * 8;
        __builtin_amdgcn_global_load_lds((__attribute__((address_space(1))) void*)src,
                                         (__attribute__((address_space(3))) void*)(lds_base + rchunk * 32),
                                         16, 0, 0);
    }
}

__device__ __forceinline__ void stage64(const bf16* __restrict__ src_base, int ld,
                                        int row0, int k0, bf16* lds_base, int w, int l)
{
    const bf16* src = src_base + (long)(row0 + w * 16 + (l >> 2)) * ld + k0 + (l & 3) * 8;
    __builtin_amdgcn_global_load_lds((__attribute__((address_space(1))) void*)src,
                                     (__attribute__((address_space(3))) void*)(lds_base + w * 16 * 32),
                                     16, 0, 0);
}

// ---------------- 128x128 MFMA GEMM body: C = A(M,K) @ BT(N,K)^T ------------
// MODE 0: bf16 out +bias[col]    1: bf16 out +bias[row]
template <int MODE>
__device__ __forceinline__ void gemm_body(
    const bf16* __restrict__ Ab, int lda, const bf16* __restrict__ Bb, int ldb,
    bf16* __restrict__ Cp, int ldc, int K, int bm, int bn,
    const float* __restrict__ bias, char* smem)
{
    bf16* As0 = (bf16*)smem;             // [2][128*32]
    bf16* Bs0 = (bf16*)(smem + 16384);
    const int tid = threadIdx.x;
    const int w = tid >> 6, l = tid & 63;
    const int wr = w >> 1, wc = w & 1;

    f32x4 acc[4][4];
#pragma unroll
    for (int i = 0; i < 4; ++i)
#pragma unroll
        for (int j = 0; j < 4; ++j) acc[i][j] = (f32x4){0.f,0.f,0.f,0.f};

    const int nkt = K >> 5;
    stage_tile_128x32(Ab, lda, bm, 0, As0, w, l);
    stage_tile_128x32(Bb, ldb, bn, 0, Bs0, w, l);
    __syncthreads();

    const int fr = l & 15;
    const int ko = (l >> 4) * 8;

    for (int kt = 0; kt < nkt; ++kt) {
        const int cur = kt & 1;
        bf16* Asc = As0 + cur * 4096;
        bf16* Bsc = Bs0 + cur * 4096;
        if (kt + 1 < nkt) {
            stage_tile_128x32(Ab, lda, bm, (kt + 1) << 5, As0 + (cur ^ 1) * 4096, w, l);
            stage_tile_128x32(Bb, ldb, bn, (kt + 1) << 5, Bs0 + (cur ^ 1) * 4096, w, l);
        }
        bf16x8 af[4], bfv[4];
#pragma unroll
        for (int mi = 0; mi < 4; ++mi)
            af[mi] = *(const bf16x8*)(&Asc[(wr * 64 + mi * 16 + fr) * 32 + ko]);
#pragma unroll
        for (int ni = 0; ni < 4; ++ni)
            bfv[ni] = *(const bf16x8*)(&Bsc[(wc * 64 + ni * 16 + fr) * 32 + ko]);
#pragma unroll
        for (int mi = 0; mi < 4; ++mi)
#pragma unroll
            for (int ni = 0; ni < 4; ++ni)
                acc[mi][ni] = __builtin_amdgcn_mfma_f32_16x16x32_bf16(af[mi], bfv[ni], acc[mi][ni], 0, 0, 0);
        __syncthreads();
    }

    // C/D layout: col = lane&15, row = (lane>>4)*4 + reg
    const int crow0 = bm + wr * 64 + (l >> 4) * 4;
    const int ccol0 = bn + wc * 64 + fr;
#pragma unroll
    for (int mi = 0; mi < 4; ++mi)
#pragma unroll
        for (int ni = 0; ni < 4; ++ni)
#pragma unroll
            for (int r = 0; r < 4; ++r) {
                const int row = crow0 + mi * 16 + r;
                const int col = ccol0 + ni * 16;
                const float v = acc[mi][ni][r];
                if constexpr (MODE == 0) {
                    Cp[(long)row * ldc + col] = (bf16)(v + bias[col]);
                } else {
                    Cp[(long)row * ldc + col] = (bf16)(v + bias[row]);
                }
            }
}

// --------- megaGEMM: qk (256 tiles 128^2) + vT (128 tiles 128^2) ------------
// R6-exact work mapping + bijective XCD swizzle (384 = 8 x 48 exactly):
// each XCD gets a contiguous run of tile-groups -> B-panel reuse in its L2.
__global__ __launch_bounds__(256, 2)
void megaGEMM(const bf16* __restrict__ featbf, const bf16* __restrict__ WqkT,
              const bf16* __restrict__ WvT, bf16* __restrict__ qkbf, bf16* __restrict__ vTbf,
              const float* __restrict__ biasqk, const float* __restrict__ bv)
{
    __shared__ char smem[32768];
    const unsigned bid = (blockIdx.x % 8u) * 48u + (blockIdx.x / 8u);  // bijective XCD swizzle
    const unsigned g = bid / 3u, r = bid % 3u;
    if (r < 2) {
        const unsigned t = g * 2 + r;          // 0..255
        gemm_body<0>(featbf, 1024, WqkT, 1024, qkbf, 2048, 1024,
                     (t & 15) * 128, (t >> 4) * 128, biasqk, smem);
    } else {
        const int img = g >> 5, rem = g & 31;  // 32 tiles/img: 8 m x 4 n
        gemm_body<1>(WvT, 1024, featbf + (long)img * 524288, 1024,
                     vTbf + (long)img * 524288, 512, 1024,
                     (rem >> 2) * 128, (rem & 3) * 128, bv, smem);
    }
}

// --------- attn64: S = q@k^T/32 (+rel on kh==0), 64x64 tiles, split-K x2 ----
__global__ __launch_bounds__(256, 4)
void attn64(const bf16* __restrict__ qk, float* __restrict__ S0, float* __restrict__ S1,
            const float* __restrict__ ent, const float* __restrict__ tabs)
{
    __shared__ char smem[20480];
    const int img = blockIdx.z >> 1, kh = blockIdx.z & 1;
    const int bm = blockIdx.x * 64, bn = blockIdx.y * 64;
    const bf16* A = qk + (long)img * 1048576 + kh * 512;
    const bf16* B = qk + 1024 + (long)img * 1048576 + kh * 512;
    bf16* As0 = (bf16*)smem;            // [2][64*32]
    bf16* Bs0 = (bf16*)(smem + 8192);

    const int tid = threadIdx.x;
    const int w = tid >> 6, l = tid & 63;
    const int wr = w >> 1, wc = w & 1;
    const int fr = l & 15;
    const int ko = (l >> 4) * 8;

    f32x4 acc[2][2];
#pragma unroll
    for (int i = 0; i < 2; ++i)
#pragma unroll
        for (int j = 0; j < 2; ++j) acc[i][j] = (f32x4){0.f,0.f,0.f,0.f};

    stage64(A, 2048, bm, 0, As0, w, l);
    stage64(B, 2048, bn, 0, Bs0, w, l);
    __syncthreads();

    for (int kt = 0; kt < 16; ++kt) {
        const int cur = kt & 1;
        bf16* Asc = As0 + cur * 2048;
        bf16* Bsc = Bs0 + cur * 2048;
        if (kt + 1 < 16) {
            stage64(A, 2048, bm, (kt + 1) << 5, As0 + (cur ^ 1) * 2048, w, l);
            stage64(B, 2048, bn, (kt + 1) << 5, Bs0 + (cur ^ 1) * 2048, w, l);
        }
        bf16x8 af[2], bfv[2];
#pragma unroll
        for (int mi = 0; mi < 2; ++mi)
            af[mi] = *(const bf16x8*)(&Asc[(wr * 32 + mi * 16 + fr) * 32 + ko]);
#pragma unroll
        for (int ni = 0; ni < 2; ++ni)
            bfv[ni] = *(const bf16x8*)(&Bsc[(wc * 32 + ni * 16 + fr) * 32 + ko]);
#pragma unroll
        for (int mi = 0; mi < 2; ++mi)
#pragma unroll
            for (int ni = 0; ni < 2; ++ni)
                acc[mi][ni] = __builtin_amdgcn_mfma_f32_16x16x32_bf16(af[mi], bfv[ni], acc[mi][ni], 0, 0, 0);
        __syncthreads();
    }

    const float scale = 0.03125f;
    float* Sout = (kh == 0 ? S0 : S1) + (long)img * 262144;

    if (kh == 1) {
#pragma unroll
        for (int mi = 0; mi < 2; ++mi)
#pragma unroll
            for (int ni = 0; ni < 2; ++ni)
#pragma unroll
                for (int r = 0; r < 4; ++r) {
                    const int rowl = wr * 32 + mi * 16 + (l >> 4) * 4 + r;
                    const int coll = wc * 32 + ni * 16 + fr;
                    Sout[(long)(bm + rowl) * 512 + bn + coll] = acc[mi][ni][r] * scale;
                }
        return;
    }

    // kh==0: add rel bias (reshape-quirk semantics). b = col>>7 uniform per tile.
    float* stab = (float*)smem;        // 4096 floats (16KB)
    float* RA   = stab + 4096;         // 64 row-entity values
    float* SA   = RA + 64;             // 260 source-entity values
    float* SE   = SA + 260;
    float* SL   = SE + 260;
    const int b   = bn >> 7;
    const int jj0 = (bn & 64) * 4;     // 0 or 256
    for (int i = tid; i < 4096; i += 256) stab[i] = tabs[i];
    {
        const int eb = img * 512;
        if (tid < 64) RA[tid] = ent[b * 2048 + eb + bm + tid];
        for (int u = tid; u < 260 && jj0 + u < 512; u += 256) {
            SA[u] = ent[b * 2048 + eb + jj0 + u];
            if (b < 2) {
                SE[u] = ent[(4 + b) * 2048 + eb + jj0 + u];
                SL[u] = ent[(2 + b) * 2048 + eb + jj0 + u];
            }
        }
    }
    __syncthreads();
#pragma unroll
    for (int ni = 0; ni < 2; ++ni) {
        const int coll = wc * 32 + ni * 16 + fr;
        const int u0   = 4 * coll;
        const float sA0 = SA[u0], sA1 = SA[u0+1], sA2 = SA[u0+2], sA3 = SA[u0+3];
        float sE0=0.f,sE1=0.f,sE2=0.f,sE3=0.f, sL0=0.f,sL1=0.f,sL2=0.f,sL3=0.f;
        if (b < 2) {
            sE0 = SE[u0]; sE1 = SE[u0+1]; sE2 = SE[u0+2]; sE3 = SE[u0+3];
            sL0 = SL[u0]; sL1 = SL[u0+1]; sL2 = SL[u0+2]; sL3 = SL[u0+3];
        }
#pragma unroll
        for (int mi = 0; mi < 2; ++mi)
#pragma unroll
            for (int r = 0; r < 4; ++r) {
                const int rowl = wr * 32 + mi * 16 + (l >> 4) * 4 + r;
                const float ai = RA[rowl];
                float d0, d1, d2, d3;
                if (b < 2) {
                    d0 = __logf(fmaxf(fabsf(ai - sA0), sE0)) - sL0;
                    d1 = __logf(fmaxf(fabsf(ai - sA1), sE1)) - sL1;
                    d2 = __logf(fmaxf(fabsf(ai - sA2), sE2)) - sL2;
                    d3 = __logf(fmaxf(fabsf(ai - sA3), sE3)) - sL3;
                } else {
                    d0 = ai - sA0; d1 = ai - sA1; d2 = ai - sA2; d3 = ai - sA3;
                }
                float relv = look(stab,        d0) + look(stab + 1024, d1)
                           + look(stab + 2048, d2) + look(stab + 3072, d3);
                Sout[(long)(bm + rowl) * 512 + bn + coll] = acc[mi][ni][r] * scale + relv;
            }
    }
}

// ---------------- row softmax over S0+S1 (512 wide) -> bf16 -----------------
__global__ __launch_bounds__(256)
void softmax2(const float* __restrict__ S0, const float* __restrict__ S1, bf16* __restrict__ P)
{
    const long row = blockIdx.x;
    const int t = threadIdx.x;
    float x0 = S0[row * 512 + t]       + S1[row * 512 + t];
    float x1 = S0[row * 512 + t + 256] + S1[row * 512 + t + 256];
    float mx = fmaxf(x0, x1);
#pragma unroll
    for (int off = 32; off; off >>= 1) mx = fmaxf(mx, __shfl_xor(mx, off));
    __shared__ float redm[4], reds[4];
    if ((t & 63) == 0) redm[t >> 6] = mx;
    __syncthreads();
    mx = fmaxf(fmaxf(redm[0], redm[1]), fmaxf(redm[2], redm[3]));
    float e0 = __expf(x0 - mx), e1 = __expf(x1 - mx);
    float sm = e0 + e1;
#pragma unroll
    for (int off = 32; off; off >>= 1) sm += __shfl_xor(sm, off);
    if ((t & 63) == 0) reds[t >> 6] = sm;
    __syncthreads();
    sm = (reds[0] + reds[1]) + (reds[2] + reds[3]);
    float inv = 1.0f / sm;
    P[row * 512 + t]       = (bf16)(e0 * inv);
    P[row * 512 + t + 256] = (bf16)(e1 * inv);
}

// --------- pv64: out = P @ vT^T, 64x64 tiles, + bn2 column partials ---------
__global__ __launch_bounds__(256, 4)
void pv64(const bf16* __restrict__ P, const bf16* __restrict__ vT, float* __restrict__ out,
          float* __restrict__ psum, float* __restrict__ psq)
{
    __shared__ char smem[16384];
    const int img = blockIdx.z;
    const int bm = blockIdx.x * 64, bn = blockIdx.y * 64;
    const bf16* A = P  + (long)img * 262144;   // 512x512
    const bf16* B = vT + (long)img * 524288;   // 1024x512
    float* C = out + (long)img * 524288;
    bf16* As0 = (bf16*)smem;
    bf16* Bs0 = (bf16*)(smem + 8192);

    const int tid = threadIdx.x;
    const int w = tid >> 6, l = tid & 63;
    const int wr = w >> 1, wc = w & 1;
    const int fr = l & 15;
    const int ko = (l >> 4) * 8;

    f32x4 acc[2][2];
#pragma unroll
    for (int i = 0; i < 2; ++i)
#pragma unroll
        for (int j = 0; j < 2; ++j) acc[i][j] = (f32x4){0.f,0.f,0.f,0.f};

    stage64(A, 512, bm, 0, As0, w, l);
    stage64(B, 512, bn, 0, Bs0, w, l);
    __syncthreads();

    for (int kt = 0; kt < 16; ++kt) {
        const int cur = kt & 1;
        bf16* Asc = As0 + cur * 2048;
        bf16* Bsc = Bs0 + cur * 2048;
        if (kt + 1 < 16) {
            stage64(A, 512, bm, (kt + 1) << 5, As0 + (cur ^ 1) * 2048, w, l);
            stage64(B, 512, bn, (kt + 1) << 5, Bs0 + (cur ^ 1) * 2048, w, l);
        }
        bf16x8 af[2], bfv[2];
#pragma unroll
        for (int mi = 0; mi < 2; ++mi)
            af[mi] = *(const bf16x8*)(&Asc[(wr * 32 + mi * 16 + fr) * 32 + ko]);
#pragma unroll
        for (int ni = 0; ni < 2; ++ni)
            bfv[ni] = *(const bf16x8*)(&Bsc[(wc * 32 + ni * 16 + fr) * 32 + ko]);
#pragma unroll
        for (int mi = 0; mi < 2; ++mi)
#pragma unroll
            for (int ni = 0; ni < 2; ++ni)
                acc[mi][ni] = __builtin_amdgcn_mfma_f32_16x16x32_bf16(af[mi], bfv[ni], acc[mi][ni], 0, 0, 0);
        __syncthreads();
    }

#pragma unroll
    for (int mi = 0; mi < 2; ++mi)
#pragma unroll
        for (int ni = 0; ni < 2; ++ni)
#pragma unroll
            for (int r = 0; r < 4; ++r) {
                const int rowl = wr * 32 + mi * 16 + (l >> 4) * 4 + r;
                const int coll = wc * 32 + ni * 16 + fr;
                C[(long)(bm + rowl) * 1024 + bn + coll] = acc[mi][ni][r];
            }

    // deterministic bn2 column partials (rows of this tile)
    float s_[2], q_[2];
#pragma unroll
    for (int ni = 0; ni < 2; ++ni) {
        float s = 0.f, q = 0.f;
#pragma unroll
        for (int mi = 0; mi < 2; ++mi)
#pragma unroll
            for (int r = 0; r < 4; ++r) { float v = acc[mi][ni][r]; s += v; q += v * v; }
        s_[ni] = s; q_[ni] = q;
    }
#pragma unroll
    for (int ni = 0; ni < 2; ++ni) {
        s_[ni] += __shfl_xor(s_[ni], 16); s_[ni] += __shfl_xor(s_[ni], 32);
        q_[ni] += __shfl_xor(q_[ni], 16); q_[ni] += __shfl_xor(q_[ni], 32);
    }
    float* lred = (float*)smem;   // [wr][sq][64]
    __syncthreads();
    if (l < 16) {
#pragma unroll
        for (int ni = 0; ni < 2; ++ni) {
            const int c = wc * 32 + ni * 16 + l;
            lred[(wr * 2 + 0) * 64 + c] = s_[ni];
            lred[(wr * 2 + 1) * 64 + c] = q_[ni];
        }
    }
    __syncthreads();
    if (tid < 64) {
        const int chunk = img * 8 + blockIdx.x;
        psum[chunk * 1024 + bn + tid] = lred[0 * 64 + tid] + lred[2 * 64 + tid];
        psq [chunk * 1024 + bn + tid] = lred[1 * 64 + tid] + lred[3 * 64 + tid];
    }
}

// ---------------------------------------------------------------------------
extern "C" void kernel_launch(void* const* d_in, const int* in_sizes, int n_in,
                              void* d_out, int out_size, void* d_ws, size_t ws_size,
                              hipStream_t stream)
{
    const float* box_features = (const float*)d_in[0];
    const float* boxes  = (const float*)d_in[1];
    const float* bn1_g  = (const float*)d_in[2];
    const float* bn1_b  = (const float*)d_in[3];
    const float* Wq     = (const float*)d_in[4];
    const float* bq     = (const float*)d_in[5];
    const float* Wk     = (const float*)d_in[6];
    const float* bk     = (const float*)d_in[7];
    const float* Wv     = (const float*)d_in[8];
    const float* bv     = (const float*)d_in[9];
    const float* Wr     = (const float*)d_in[10];
    const float* br     = (const float*)d_in[11];
    const float* bn2_g  = (const float*)d_in[12];
    const float* bn2_b  = (const float*)d_in[13];
    float* out = (float*)d_out;

    char* ws = (char*)d_ws;
    const long MB = 1024 * 1024;
    float* psum   = (float*)(ws + 0);            // 128x1024 f32
    float* psq    = (float*)(ws + 512 * 1024);
    float* biasqk = (float*)(ws + 1 * MB);               // 2048 f32
    float* ent    = (float*)(ws + 1 * MB + 65536);       // 6 x 2048 f32
    float* tabs   = (float*)(ws + 1 * MB + 131072);      // 4096 f32
    bf16*  featbf = (bf16*)(ws + 2 * MB);        // 2048x1024 bf16 (4MB)
    bf16*  WqkT   = (bf16*)(ws + 6 * MB);        // 2048x1024 bf16 (4MB) [WqT;WkT]
    float* Sbuf1  = (float*)(ws + 6 * MB);       // aliases WqkT (dead after megaGEMM)
    bf16*  WvT    = (bf16*)(ws + 10 * MB);       // 1024x1024 bf16 (2MB)
    bf16*  qkbf   = (bf16*)(ws + 12 * MB);       // 2048x2048 bf16 (8MB)
    bf16*  vTbf   = (bf16*)(ws + 20 * MB);       // 4x1024x512 bf16 (4MB)
    float* Sbuf0  = (float*)(ws + 24 * MB);      // 4x512x512 f32 (4MB)
    bf16*  Pbuf   = (bf16*)(ws + 28 * MB);       // 4x512x512 bf16 (2MB)

    prep<<<dim3(901, 1, 1), dim3(256, 1, 1), 0, stream>>>(
        Wq, Wk, Wv, WqkT, WqkT + 1024 * 1024, WvT, bq, bk, biasqk,
        box_features, psum, psq, boxes, Wr, br, ent, tabs);

    bn_final_apply<NCH1, 1><<<dim3(16, 16, 1), dim3(256, 1, 1), 0, stream>>>(
        box_features, psum, psq, bn1_g, bn1_b, featbf);

    megaGEMM<<<dim3(384, 1, 1), dim3(256, 1, 1), 0, stream>>>(
        featbf, WqkT, WvT, qkbf, vTbf, biasqk, bv);

    attn64<<<dim3(8, 8, 8), dim3(256, 1, 1), 0, stream>>>(qkbf, Sbuf0, Sbuf1, ent, tabs);

    softmax2<<<dim3(2048, 1, 1), dim3(256, 1, 1), 0, stream>>>(Sbuf0, Sbuf1, Pbuf);

    pv64<<<dim3(8, 16, 4), dim3(256, 1, 1), 0, stream>>>(Pbuf, vTbf, out, psum, psq);

    bn_final_apply<32, 0><<<dim3(16, 16, 1), dim3(256, 1, 1), 0, stream>>>(
        out, psum, psq, bn2_g, bn2_b, out);
}

// Round 13
// 82.452 us; speedup vs baseline: 7.0202x; 1.0529x over previous
//
#include <hip/hip_runtime.h>
#include <math.h>

typedef __bf16 bf16;
typedef __attribute__((ext_vector_type(8))) __bf16 bf16x8;
typedef __attribute__((ext_vector_type(4))) __bf16 bf16x4;
typedef __attribute__((ext_vector_type(4))) float f32x4;

#define NCH1 128  // row chunks for bn1 stats
#define RPC1 16   // rows per chunk

// rel-PE table domain: covers ln(1e-3) .. ln(57.5) and dw/dh range
#define XD0   (-6.93f)
#define XSPAN (11.03f)
#define XINVH (1023.f / 11.03f)

// ---------------------------------------------------------------------------
// prep mega-kernel: 901 blocks
// ---------------------------------------------------------------------------
__global__ __launch_bounds__(256)
void prep(const float* __restrict__ Wq, const float* __restrict__ Wk, const float* __restrict__ Wv,
          bf16* __restrict__ T0, bf16* __restrict__ T1, bf16* __restrict__ T2,
          const float* __restrict__ bq, const float* __restrict__ bk, float* __restrict__ biasqk,
          const float* __restrict__ X, float* __restrict__ psum, float* __restrict__ psq,
          const float* __restrict__ boxes, const float* __restrict__ Wr, const float* __restrict__ br,
          float* __restrict__ ent, float* __restrict__ tabs)
{
    __shared__ float tile[64][65];
    const int bid = blockIdx.x;
    const int tid = threadIdx.x;

    if (bid < 768) {                       // ---- weight transpose+cvt
        const int mat = bid >> 8, g2 = bid & 255;
        const float* W = (mat == 0) ? Wq : (mat == 1) ? Wk : Wv;
        bf16* T        = (mat == 0) ? T0 : (mat == 1) ? T1 : T2;
        const int bx = (g2 & 15) * 64, by = (g2 >> 4) * 64;
        const int tx = tid & 63, ty = tid >> 6;
#pragma unroll
        for (int i = 0; i < 16; ++i)
            tile[ty + i * 4][tx] = W[(long)(by + ty + i * 4) * 1024 + bx + tx];
        __syncthreads();
#pragma unroll
        for (int i = 0; i < 16; ++i)
            T[(long)(bx + ty + i * 4) * 1024 + by + tx] = (bf16)tile[tx][ty + i * 4];
    } else if (bid < 896) {                // ---- bn1 colstats partial
        const int c4 = tid;
        const long r0 = (long)(bid - 768) * RPC1;
        const float4* Xv = (const float4*)X;
        float4 s = {0.f,0.f,0.f,0.f}, q = {0.f,0.f,0.f,0.f};
#pragma unroll
        for (int r = 0; r < RPC1; ++r) {
            float4 x = Xv[(r0 + r) * 256 + c4];
            s.x += x.x; s.y += x.y; s.z += x.z; s.w += x.w;
            q.x += x.x*x.x; q.y += x.y*x.y; q.z += x.z*x.z; q.w += x.w*x.w;
        }
        ((float4*)psum)[(bid - 768) * 256 + c4] = s;
        ((float4*)psq) [(bid - 768) * 256 + c4] = q;
    } else if (bid == 896) {               // ---- entity values + bias pack
        for (int e = tid; e < 2048; e += 256) {
            float4 b4 = ((const float4*)boxes)[e];
            float w = b4.z, h = b4.w;
            ent[0*2048+e] = b4.x + 0.5f * w;   // cx
            ent[1*2048+e] = b4.y + 0.5f * h;   // cy
            ent[2*2048+e] = __logf(w);         // lw
            ent[3*2048+e] = __logf(h);         // lh
            ent[4*2048+e] = 1e-3f * w;         // ew
            ent[5*2048+e] = 1e-3f * h;         // eh
        }
        for (int i = tid; i < 2048; i += 256)
            biasqk[i] = (i < 1024) ? bq[i] : bk[i - 1024];
    } else {                               // ---- rel tables per weight slot
        const int c = bid - 897;           // weight slot 0..3
        float* tb = tabs + c * 1024;
        const float brq = 0.25f * br[0];
        const float hstep = XSPAN / 1023.f;
        for (int e = tid; e < 1024; e += 256) {
            float d = XD0 + hstep * (float)e;
            float a = brq;
#pragma unroll
            for (int k = 0; k < 16; ++k) {
                float tk = exp2f(-1.24572303558f * (float)k);  // 1000^(-k/8)
                float s_, c_;
                __sincosf(d * tk, &s_, &c_);
                a += s_ * Wr[c * 32 + k] + c_ * Wr[c * 32 + 16 + k];
            }
            tb[e] = a;
        }
    }
}

// ------- fused: finalize stats (per 64-col stripe) + apply BN ---------------
template <int NCH_, int BF16OUT>
__global__ __launch_bounds__(256)
void bn_final_apply(const float* __restrict__ X, const float* __restrict__ psum,
                    const float* __restrict__ psq, const float* __restrict__ g,
                    const float* __restrict__ b, void* __restrict__ Yp)
{
    __shared__ float ls[4][64], lq[4][64], ssc[64], ssh[64];
    const int t  = threadIdx.x;
    const int cs = blockIdx.x;
    const int rc = blockIdx.y;
    const int col_l = t & 63, part = t >> 6;
    const int col = cs * 64 + col_l;
    constexpr int CPT = NCH_ / 4;
    float s = 0.f, q = 0.f;
#pragma unroll
    for (int i = 0; i < CPT; ++i) {
        int ch = part * CPT + i;
        s += psum[ch * 1024 + col];
        q += psq [ch * 1024 + col];
    }
    ls[part][col_l] = s; lq[part][col_l] = q;
    __syncthreads();
    if (t < 64) {
        float S = ls[0][t]+ls[1][t]+ls[2][t]+ls[3][t];
        float Q = lq[0][t]+lq[1][t]+lq[2][t]+lq[3][t];
        float m = S / 2048.f;
        float v = Q / 2048.f - m*m;
        float inv = 1.0f / sqrtf(v + 1e-5f);
        float sc = g[cs*64+t] * inv;
        ssc[t] = sc; ssh[t] = b[cs*64+t] - m*sc;
    }
    __syncthreads();
    const int f = t & 15, rsub = t >> 4;
    float4 sc4 = ((const float4*)ssc)[f];
    float4 sh4 = ((const float4*)ssh)[f];
#pragma unroll
    for (int it = 0; it < 8; ++it) {
        int row = rc*128 + it*16 + rsub;
        float4 x = ((const float4*)(X + (long)row*1024 + cs*64))[f];
        float4 rv;
        rv.x = x.x*sc4.x + sh4.x;
        rv.y = x.y*sc4.y + sh4.y;
        rv.z = x.z*sc4.z + sh4.z;
        rv.w = x.w*sc4.w + sh4.w;
        if constexpr (BF16OUT) {
            bf16x4 y;
            y[0]=(bf16)rv.x; y[1]=(bf16)rv.y; y[2]=(bf16)rv.z; y[3]=(bf16)rv.w;
            ((bf16x4*)((bf16*)Yp + (long)row*1024 + cs*64))[f] = y;
        } else {
            ((float4*)((float*)Yp + (long)row*1024 + cs*64))[f] = rv;
        }
    }
}

// ---------------- rel table lookup ------------------------------------------
__device__ __forceinline__ float look(const float* tab, float d)
{
    float t = (d - XD0) * XINVH;
    t = fminf(fmaxf(t, 0.f), 1022.999f);
    float fi = floorf(t);
    int i = (int)fi;
    float a = tab[i], b = tab[i + 1];
    return a + (b - a) * (t - fi);
}

// ---------------- staging helpers -------------------------------------------
// BK=64 swizzled stage: LDS layout [128][64] bf16 with granule-XOR st-swizzle.
// Linear LDS dest (wave-uniform base + lane*16, m104); the per-lane GLOBAL
// source granule is pre-permuted (m173): LDS[row][g] = global[row][g ^ (row&7)],
// rows-per-instr = 8 so row&7 == l>>3 (pure lane function).
__device__ __forceinline__ void stage_128x64_swz(const bf16* __restrict__ src_base, int ld,
                                                 int row0, int k0, bf16* lds_base, int w, int l)
{
    const int rsub = l >> 3;                    // 0..7
    const int gsrc = ((l & 7) ^ rsub) * 8;      // swizzled source granule (elements)
#pragma unroll
    for (int t = 0; t < 4; ++t) {
        const int rchunk = w * 32 + t * 8;      // multiple of 8 -> (row&7)==rsub
        const bf16* src = src_base + (long)(row0 + rchunk + rsub) * ld + k0 + gsrc;
        __builtin_amdgcn_global_load_lds((__attribute__((address_space(1))) void*)src,
                                         (__attribute__((address_space(3))) void*)(lds_base + rchunk * 64),
                                         16, 0, 0);
    }
}

// swizzled fragment read: logical (row, k-granule kk*4+lo) -> physical granule
__device__ __forceinline__ bf16x8 frag_swz(const bf16* __restrict__ Ts, int row, int kk, int lo)
{
    const int gp = ((kk << 2) + lo) ^ (row & 7);
    return *(const bf16x8*)(Ts + row * 64 + gp * 8);
}

__device__ __forceinline__ void stage64(const bf16* __restrict__ src_base, int ld,
                                        int row0, int k0, bf16* lds_base, int w, int l)
{
    const bf16* src = src_base + (long)(row0 + w * 16 + (l >> 2)) * ld + k0 + (l & 3) * 8;
    __builtin_amdgcn_global_load_lds((__attribute__((address_space(1))) void*)src,
                                     (__attribute__((address_space(3))) void*)(lds_base + w * 16 * 32),
                                     16, 0, 0);
}

// ---------------- 128x128 MFMA GEMM body, BK=64: C = A(M,K) @ BT(N,K)^T -----
// MODE 0: bf16 out +bias[col]    1: bf16 out +bias[row]
// LDS: 2 dbuf x (As 16KB + Bs 16KB) = 64KB -> 2 blocks/CU (128KB <= 160KB).
template <int MODE>
__device__ __forceinline__ void gemm_body(
    const bf16* __restrict__ Ab, int lda, const bf16* __restrict__ Bb, int ldb,
    bf16* __restrict__ Cp, int ldc, int K, int bm, int bn,
    const float* __restrict__ bias, char* smem)
{
    bf16* As0 = (bf16*)smem;             // [2][128*64] 16KB each
    bf16* Bs0 = (bf16*)(smem + 32768);
    const int tid = threadIdx.x;
    const int w = tid >> 6, l = tid & 63;
    const int wr = w >> 1, wc = w & 1;

    f32x4 acc[4][4];
#pragma unroll
    for (int i = 0; i < 4; ++i)
#pragma unroll
        for (int j = 0; j < 4; ++j) acc[i][j] = (f32x4){0.f,0.f,0.f,0.f};

    const int nkt = K >> 6;                  // BK=64
    stage_128x64_swz(Ab, lda, bm, 0, As0, w, l);
    stage_128x64_swz(Bb, ldb, bn, 0, Bs0, w, l);
    __syncthreads();

    const int fr = l & 15;
    const int lo = l >> 4;                   // 0..3

    for (int kt = 0; kt < nkt; ++kt) {
        const int cur = kt & 1;
        bf16* Asc = As0 + cur * 8192;
        bf16* Bsc = Bs0 + cur * 8192;
        if (kt + 1 < nkt) {
            stage_128x64_swz(Ab, lda, bm, (kt + 1) << 6, As0 + (cur ^ 1) * 8192, w, l);
            stage_128x64_swz(Bb, ldb, bn, (kt + 1) << 6, Bs0 + (cur ^ 1) * 8192, w, l);
        }
#pragma unroll
        for (int kk = 0; kk < 2; ++kk) {
            bf16x8 af[4], bfv[4];
#pragma unroll
            for (int mi = 0; mi < 4; ++mi)
                af[mi] = frag_swz(Asc, wr * 64 + mi * 16 + fr, kk, lo);
#pragma unroll
            for (int ni = 0; ni < 4; ++ni)
                bfv[ni] = frag_swz(Bsc, wc * 64 + ni * 16 + fr, kk, lo);
#pragma unroll
            for (int mi = 0; mi < 4; ++mi)
#pragma unroll
                for (int ni = 0; ni < 4; ++ni)
                    acc[mi][ni] = __builtin_amdgcn_mfma_f32_16x16x32_bf16(af[mi], bfv[ni], acc[mi][ni], 0, 0, 0);
        }
        __syncthreads();
    }

    // C/D layout: col = lane&15, row = (lane>>4)*4 + reg
    const int crow0 = bm + wr * 64 + lo * 4;
    const int ccol0 = bn + wc * 64 + fr;
#pragma unroll
    for (int mi = 0; mi < 4; ++mi)
#pragma unroll
        for (int ni = 0; ni < 4; ++ni)
#pragma unroll
            for (int r = 0; r < 4; ++r) {
                const int row = crow0 + mi * 16 + r;
                const int col = ccol0 + ni * 16;
                const float v = acc[mi][ni][r];
                if constexpr (MODE == 0) {
                    Cp[(long)row * ldc + col] = (bf16)(v + bias[col]);
                } else {
                    Cp[(long)row * ldc + col] = (bf16)(v + bias[row]);
                }
            }
}

// --------- megaGEMM: qk (256 tiles 128^2) + vT (128 tiles 128^2) ------------
// R6-exact work mapping + bijective XCD swizzle (384 = 8 x 48 exactly).
__global__ __launch_bounds__(256, 2)
void megaGEMM(const bf16* __restrict__ featbf, const bf16* __restrict__ WqkT,
              const bf16* __restrict__ WvT, bf16* __restrict__ qkbf, bf16* __restrict__ vTbf,
              const float* __restrict__ biasqk, const float* __restrict__ bv)
{
    __shared__ char smem[65536];
    const unsigned bid = (blockIdx.x % 8u) * 48u + (blockIdx.x / 8u);  // bijective XCD swizzle
    const unsigned g = bid / 3u, r = bid % 3u;
    if (r < 2) {
        const unsigned t = g * 2 + r;          // 0..255
        gemm_body<0>(featbf, 1024, WqkT, 1024, qkbf, 2048, 1024,
                     (t & 15) * 128, (t >> 4) * 128, biasqk, smem);
    } else {
        const int img = g >> 5, rem = g & 31;  // 32 tiles/img: 8 m x 4 n
        gemm_body<1>(WvT, 1024, featbf + (long)img * 524288, 1024,
                     vTbf + (long)img * 524288, 512, 1024,
                     (rem >> 2) * 128, (rem & 3) * 128, bv, smem);
    }
}

// --------- attn64: S = q@k^T/32 (+rel on kh==0), 64x64 tiles, split-K x2 ----
__global__ __launch_bounds__(256, 4)
void attn64(const bf16* __restrict__ qk, float* __restrict__ S0, float* __restrict__ S1,
            const float* __restrict__ ent, const float* __restrict__ tabs)
{
    __shared__ char smem[20480];
    const int img = blockIdx.z >> 1, kh = blockIdx.z & 1;
    const int bm = blockIdx.x * 64, bn = blockIdx.y * 64;
    const bf16* A = qk + (long)img * 1048576 + kh * 512;
    const bf16* B = qk + 1024 + (long)img * 1048576 + kh * 512;
    bf16* As0 = (bf16*)smem;            // [2][64*32]
    bf16* Bs0 = (bf16*)(smem + 8192);

    const int tid = threadIdx.x;
    const int w = tid >> 6, l = tid & 63;
    const int wr = w >> 1, wc = w & 1;
    const int fr = l & 15;
    const int ko = (l >> 4) * 8;

    f32x4 acc[2][2];
#pragma unroll
    for (int i = 0; i < 2; ++i)
#pragma unroll
        for (int j = 0; j < 2; ++j) acc[i][j] = (f32x4){0.f,0.f,0.f,0.f};

    stage64(A, 2048, bm, 0, As0, w, l);
    stage64(B, 2048, bn, 0, Bs0, w, l);
    __syncthreads();

    for (int kt = 0; kt < 16; ++kt) {
        const int cur = kt & 1;
        bf16* Asc = As0 + cur * 2048;
        bf16* Bsc = Bs0 + cur * 2048;
        if (kt + 1 < 16) {
            stage64(A, 2048, bm, (kt + 1) << 5, As0 + (cur ^ 1) * 2048, w, l);
            stage64(B, 2048, bn, (kt + 1) << 5, Bs0 + (cur ^ 1) * 2048, w, l);
        }
        bf16x8 af[2], bfv[2];
#pragma unroll
        for (int mi = 0; mi < 2; ++mi)
            af[mi] = *(const bf16x8*)(&Asc[(wr * 32 + mi * 16 + fr) * 32 + ko]);
#pragma unroll
        for (int ni = 0; ni < 2; ++ni)
            bfv[ni] = *(const bf16x8*)(&Bsc[(wc * 32 + ni * 16 + fr) * 32 + ko]);
#pragma unroll
        for (int mi = 0; mi < 2; ++mi)
#pragma unroll
            for (int ni = 0; ni < 2; ++ni)
                acc[mi][ni] = __builtin_amdgcn_mfma_f32_16x16x32_bf16(af[mi], bfv[ni], acc[mi][ni], 0, 0, 0);
        __syncthreads();
    }

    const float scale = 0.03125f;
    float* Sout = (kh == 0 ? S0 : S1) + (long)img * 262144;

    if (kh == 1) {
#pragma unroll
        for (int mi = 0; mi < 2; ++mi)
#pragma unroll
            for (int ni = 0; ni < 2; ++ni)
#pragma unroll
                for (int r = 0; r < 4; ++r) {
                    const int rowl = wr * 32 + mi * 16 + (l >> 4) * 4 + r;
                    const int coll = wc * 32 + ni * 16 + fr;
                    Sout[(long)(bm + rowl) * 512 + bn + coll] = acc[mi][ni][r] * scale;
                }
        return;
    }

    // kh==0: add rel bias (reshape-quirk semantics). b = col>>7 uniform per tile.
    float* stab = (float*)smem;        // 4096 floats (16KB)
    float* RA   = stab + 4096;         // 64 row-entity values
    float* SA   = RA + 64;             // 260 source-entity values
    float* SE   = SA + 260;
    float* SL   = SE + 260;
    const int b   = bn >> 7;
    const int jj0 = (bn & 64) * 4;     // 0 or 256
    for (int i = tid; i < 4096; i += 256) stab[i] = tabs[i];
    {
        const int eb = img * 512;
        if (tid < 64) RA[tid] = ent[b * 2048 + eb + bm + tid];
        for (int u = tid; u < 260 && jj0 + u < 512; u += 256) {
            SA[u] = ent[b * 2048 + eb + jj0 + u];
            if (b < 2) {
                SE[u] = ent[(4 + b) * 2048 + eb + jj0 + u];
                SL[u] = ent[(2 + b) * 2048 + eb + jj0 + u];
            }
        }
    }
    __syncthreads();
#pragma unroll
    for (int ni = 0; ni < 2; ++ni) {
        const int coll = wc * 32 + ni * 16 + fr;
        const int u0   = 4 * coll;
        const float sA0 = SA[u0], sA1 = SA[u0+1], sA2 = SA[u0+2], sA3 = SA[u0+3];
        float sE0=0.f,sE1=0.f,sE2=0.f,sE3=0.f, sL0=0.f,sL1=0.f,sL2=0.f,sL3=0.f;
        if (b < 2) {
            sE0 = SE[u0]; sE1 = SE[u0+1]; sE2 = SE[u0+2]; sE3 = SE[u0+3];
            sL0 = SL[u0]; sL1 = SL[u0+1]; sL2 = SL[u0+2]; sL3 = SL[u0+3];
        }
#pragma unroll
        for (int mi = 0; mi < 2; ++mi)
#pragma unroll
            for (int r = 0; r < 4; ++r) {
                const int rowl = wr * 32 + mi * 16 + (l >> 4) * 4 + r;
                const float ai = RA[rowl];
                float d0, d1, d2, d3;
                if (b < 2) {
                    d0 = __logf(fmaxf(fabsf(ai - sA0), sE0)) - sL0;
                    d1 = __logf(fmaxf(fabsf(ai - sA1), sE1)) - sL1;
                    d2 = __logf(fmaxf(fabsf(ai - sA2), sE2)) - sL2;
                    d3 = __logf(fmaxf(fabsf(ai - sA3), sE3)) - sL3;
                } else {
                    d0 = ai - sA0; d1 = ai - sA1; d2 = ai - sA2; d3 = ai - sA3;
                }
                float relv = look(stab,        d0) + look(stab + 1024, d1)
                           + look(stab + 2048, d2) + look(stab + 3072, d3);
                Sout[(long)(bm + rowl) * 512 + bn + coll] = acc[mi][ni][r] * scale + relv;
            }
    }
}

// ---------------- row softmax over S0+S1 (512 wide) -> bf16 -----------------
__global__ __launch_bounds__(256)
void softmax2(const float* __restrict__ S0, const float* __restrict__ S1, bf16* __restrict__ P)
{
    const long row = blockIdx.x;
    const int t = threadIdx.x;
    float x0 = S0[row * 512 + t]       + S1[row * 512 + t];
    float x1 = S0[row * 512 + t + 256] + S1[row * 512 + t + 256];
    float mx = fmaxf(x0, x1);
#pragma unroll
    for (int off = 32; off; off >>= 1) mx = fmaxf(mx, __shfl_xor(mx, off));
    __shared__ float redm[4], reds[4];
    if ((t & 63) == 0) redm[t >> 6] = mx;
    __syncthreads();
    mx = fmaxf(fmaxf(redm[0], redm[1]), fmaxf(redm[2], redm[3]));
    float e0 = __expf(x0 - mx), e1 = __expf(x1 - mx);
    float sm = e0 + e1;
#pragma unroll
    for (int off = 32; off; off >>= 1) sm += __shfl_xor(sm, off);
    if ((t & 63) == 0) reds[t >> 6] = sm;
    __syncthreads();
    sm = (reds[0] + reds[1]) + (reds[2] + reds[3]);
    float inv = 1.0f / sm;
    P[row * 512 + t]       = (bf16)(e0 * inv);
    P[row * 512 + t + 256] = (bf16)(e1 * inv);
}

// --------- pv64: out = P @ vT^T, 64x64 tiles, + bn2 column partials ---------
__global__ __launch_bounds__(256, 4)
void pv64(const bf16* __restrict__ P, const bf16* __restrict__ vT, float* __restrict__ out,
          float* __restrict__ psum, float* __restrict__ psq)
{
    __shared__ char smem[16384];
    const int img = blockIdx.z;
    const int bm = blockIdx.x * 64, bn = blockIdx.y * 64;
    const bf16* A = P  + (long)img * 262144;   // 512x512
    const bf16* B = vT + (long)img * 524288;   // 1024x512
    float* C = out + (long)img * 524288;
    bf16* As0 = (bf16*)smem;
    bf16* Bs0 = (bf16*)(smem + 8192);

    const int tid = threadIdx.x;
    const int w = tid >> 6, l = tid & 63;
    const int wr = w >> 1, wc = w & 1;
    const int fr = l & 15;
    const int ko = (l >> 4) * 8;

    f32x4 acc[2][2];
#pragma unroll
    for (int i = 0; i < 2; ++i)
#pragma unroll
        for (int j = 0; j < 2; ++j) acc[i][j] = (f32x4){0.f,0.f,0.f,0.f};

    stage64(A, 512, bm, 0, As0, w, l);
    stage64(B, 512, bn, 0, Bs0, w, l);
    __syncthreads();

    for (int kt = 0; kt < 16; ++kt) {
        const int cur = kt & 1;
        bf16* Asc = As0 + cur * 2048;
        bf16* Bsc = Bs0 + cur * 2048;
        if (kt + 1 < 16) {
            stage64(A, 512, bm, (kt + 1) << 5, As0 + (cur ^ 1) * 2048, w, l);
            stage64(B, 512, bn, (kt + 1) << 5, Bs0 + (cur ^ 1) * 2048, w, l);
        }
        bf16x8 af[2], bfv[2];
#pragma unroll
        for (int mi = 0; mi < 2; ++mi)
            af[mi] = *(const bf16x8*)(&Asc[(wr * 32 + mi * 16 + fr) * 32 + ko]);
#pragma unroll
        for (int ni = 0; ni < 2; ++ni)
            bfv[ni] = *(const bf16x8*)(&Bsc[(wc * 32 + ni * 16 + fr) * 32 + ko]);
#pragma unroll
        for (int mi = 0; mi < 2; ++mi)
#pragma unroll
            for (int ni = 0; ni < 2; ++ni)
                acc[mi][ni] = __builtin_amdgcn_mfma_f32_16x16x32_bf16(af[mi], bfv[ni], acc[mi][ni], 0, 0, 0);
        __syncthreads();
    }

#pragma unroll
    for (int mi = 0; mi < 2; ++mi)
#pragma unroll
        for (int ni = 0; ni < 2; ++ni)
#pragma unroll
            for (int r = 0; r < 4; ++r) {
                const int rowl = wr * 32 + mi * 16 + (l >> 4) * 4 + r;
                const int coll = wc * 32 + ni * 16 + fr;
                C[(long)(bm + rowl) * 1024 + bn + coll] = acc[mi][ni][r];
            }

    // deterministic bn2 column partials (rows of this tile)
    float s_[2], q_[2];
#pragma unroll
    for (int ni = 0; ni < 2; ++ni) {
        float s = 0.f, q = 0.f;
#pragma unroll
        for (int mi = 0; mi < 2; ++mi)
#pragma unroll
            for (int r = 0; r < 4; ++r) { float v = acc[mi][ni][r]; s += v; q += v * v; }
        s_[ni] = s; q_[ni] = q;
    }
#pragma unroll
    for (int ni = 0; ni < 2; ++ni) {
        s_[ni] += __shfl_xor(s_[ni], 16); s_[ni] += __shfl_xor(s_[ni], 32);
        q_[ni] += __shfl_xor(q_[ni], 16); q_[ni] += __shfl_xor(q_[ni], 32);
    }
    float* lred = (float*)smem;   // [wr][sq][64]
    __syncthreads();
    if (l < 16) {
#pragma unroll
        for (int ni = 0; ni < 2; ++ni) {
            const int c = wc * 32 + ni * 16 + l;
            lred[(wr * 2 + 0) * 64 + c] = s_[ni];
            lred[(wr * 2 + 1) * 64 + c] = q_[ni];
        }
    }
    __syncthreads();
    if (tid < 64) {
        const int chunk = img * 8 + blockIdx.x;
        psum[chunk * 1024 + bn + tid] = lred[0 * 64 + tid] + lred[2 * 64 + tid];
        psq [chunk * 1024 + bn + tid] = lred[1 * 64 + tid] + lred[3 * 64 + tid];
    }
}

// ---------------------------------------------------------------------------
extern "C" void kernel_launch(void* const* d_in, const int* in_sizes, int n_in,
                              void* d_out, int out_size, void* d_ws, size_t ws_size,
                              hipStream_t stream)
{
    const float* box_features = (const float*)d_in[0];
    const float* boxes  = (const float*)d_in[1];
    const float* bn1_g  = (const float*)d_in[2];
    const float* bn1_b  = (const float*)d_in[3];
    const float* Wq     = (const float*)d_in[4];
    const float* bq     = (const float*)d_in[5];
    const float* Wk     = (const float*)d_in[6];
    const float* bk     = (const float*)d_in[7];
    const float* Wv     = (const float*)d_in[8];
    const float* bv     = (const float*)d_in[9];
    const float* Wr     = (const float*)d_in[10];
    const float* br     = (const float*)d_in[11];
    const float* bn2_g  = (const float*)d_in[12];
    const float* bn2_b  = (const float*)d_in[13];
    float* out = (float*)d_out;

    char* ws = (char*)d_ws;
    const long MB = 1024 * 1024;
    float* psum   = (float*)(ws + 0);            // 128x1024 f32
    float* psq    = (float*)(ws + 512 * 1024);
    float* biasqk = (float*)(ws + 1 * MB);               // 2048 f32
    float* ent    = (float*)(ws + 1 * MB + 65536);       // 6 x 2048 f32
    float* tabs   = (float*)(ws + 1 * MB + 131072);      // 4096 f32
    bf16*  featbf = (bf16*)(ws + 2 * MB);        // 2048x1024 bf16 (4MB)
    bf16*  WqkT   = (bf16*)(ws + 6 * MB);        // 2048x1024 bf16 (4MB) [WqT;WkT]
    float* Sbuf1  = (float*)(ws + 6 * MB);       // aliases WqkT (dead after megaGEMM)
    bf16*  WvT    = (bf16*)(ws + 10 * MB);       // 1024x1024 bf16 (2MB)
    bf16*  qkbf   = (bf16*)(ws + 12 * MB);       // 2048x2048 bf16 (8MB)
    bf16*  vTbf   = (bf16*)(ws + 20 * MB);       // 4x1024x512 bf16 (4MB)
    float* Sbuf0  = (float*)(ws + 24 * MB);      // 4x512x512 f32 (4MB)
    bf16*  Pbuf   = (bf16*)(ws + 28 * MB);       // 4x512x512 bf16 (2MB)

    prep<<<dim3(901, 1, 1), dim3(256, 1, 1), 0, stream>>>(
        Wq, Wk, Wv, WqkT, WqkT + 1024 * 1024, WvT, bq, bk, biasqk,
        box_features, psum, psq, boxes, Wr, br, ent, tabs);

    bn_final_apply<NCH1, 1><<<dim3(16, 16, 1), dim3(256, 1, 1), 0, stream>>>(
        box_features, psum, psq, bn1_g, bn1_b, featbf);

    megaGEMM<<<dim3(384, 1, 1), dim3(256, 1, 1), 0, stream>>>(
        featbf, WqkT, WvT, qkbf, vTbf, biasqk, bv);

    attn64<<<dim3(8, 8, 8), dim3(256, 1, 1), 0, stream>>>(qkbf, Sbuf0, Sbuf1, ent, tabs);

    softmax2<<<dim3(2048, 1, 1), dim3(256, 1, 1), 0, stream>>>(Sbuf0, Sbuf1, Pbuf);

    pv64<<<dim3(8, 16, 4), dim3(256, 1, 1), 0, stream>>>(Pbuf, vTbf, out, psum, psq);

    bn_final_apply<32, 0><<<dim3(16, 16, 1), dim3(256, 1, 1), 0, stream>>>(
        out, psum, psq, bn2_g, bn2_b, out);
}